// Round 1
// baseline (711.136 us; speedup 1.0000x reference)
//
#include <hip/hip_runtime.h>

#define NV   50000
#define NEV  10000
#define NNZV 600000
#define DIM  128

// workspace layout (float offsets)
#define CT_OFF   0                   // 384*128 combined final weights, [k][o]
#define WT1_OFF  49152               // 128*128 W1 transposed, [k][o]
#define BA_OFF   65536               // 128 (A-scaled bias), pad to 256
#define A_OFF    65792               // 50048: per-vertex alpha sum
#define B_OFF    115840              // 10048: per-edge alpha sum
#define T_OFF    125888              // NE*128: T, then Xe in-place

// ---------------- weight preparation (tiny) ----------------
// Ct[k][o]: k<256  -> 0.5 * sum_m Ww[o][m] * W2w[m][k]   (W2a|W2b part)
//           k>=256 -> 0.5 * Ww[o][k-256]                  (X0 part)
// Wt1[k][o] = W1w[o][k];  bA[o] = 0.5 * sum_m Ww[o][m]*W2b_bias[m]
__global__ __launch_bounds__(128) void prep_weights(
        const float* __restrict__ W1w, const float* __restrict__ W2w,
        const float* __restrict__ W2b, const float* __restrict__ Ww,
        float* __restrict__ ws){
  int b = blockIdx.x, o = threadIdx.x;
  if (b < 384){
    float s;
    if (b < 256){
      float acc = 0.f;
      for (int m = 0; m < 128; ++m) acc += Ww[o*128 + m] * W2w[m*256 + b];
      s = 0.5f * acc;
    } else {
      s = 0.5f * Ww[o*128 + (b - 256)];
    }
    ws[CT_OFF + b*128 + o] = s;
  } else if (b < 512){
    int k = b - 384;
    ws[WT1_OFF + k*128 + o] = W1w[o*128 + k];
  } else {
    float acc = 0.f;
    for (int m = 0; m < 128; ++m) acc += Ww[o*128 + m] * W2b[m];
    ws[BA_OFF + o] = 0.5f * acc;
  }
}

// ---------------- scatter to edges: T[e] += a*X[v], B[e]+=a, A[v]+=a ----------------
__global__ __launch_bounds__(256) void scatter_edges(
        const float* __restrict__ X, const int* __restrict__ vertex,
        const int* __restrict__ edges, const float* __restrict__ alpha,
        float* __restrict__ ws){
  int i = blockIdx.x*2 + (threadIdx.x >> 7);
  int d = threadIdx.x & 127;
  int v = vertex[i]; int e = edges[i]; float a = alpha[i];
  float val = a * X[(size_t)v*DIM + d];
  atomicAdd(ws + T_OFF + (size_t)e*DIM + d, val);
  if (d == 0){
    atomicAdd(ws + B_OFF + e, a);
    atomicAdd(ws + A_OFF + v, a);
  }
}

// ---------------- Xe = T @ Wt1 + B*b1  (in-place over T) ----------------
__global__ __launch_bounds__(256) void gemm_xe(const float* __restrict__ W1b,
                                               float* __restrict__ ws){
  __shared__ float Y[32][136];
  float* T = ws + T_OFF;
  const float* Wt1 = ws + WT1_OFF;
  const float* Bs  = ws + B_OFF;
  int n0 = blockIdx.x * 32;
  int tid = threadIdx.x;
  {
    int lr = tid >> 3, lj = tid & 7;
    int gn = n0 + lr; if (gn >= NEV) gn = NEV - 1;
    const float* src = T + (size_t)gn*DIM + lj*16;
    #pragma unroll
    for (int q = 0; q < 4; ++q)
      *(float4*)(&Y[lr][lj*16 + q*4]) = *(const float4*)(src + q*4);
  }
  __syncthreads();
  int rq = tid >> 5, cq = tid & 31;
  float acc[4][4];
  #pragma unroll
  for (int u=0;u<4;++u){ acc[u][0]=0;acc[u][1]=0;acc[u][2]=0;acc[u][3]=0; }
  const float* Crow = Wt1 + cq*4;
  #pragma unroll 4
  for (int k = 0; k < 128; ++k){
    float4 c = *(const float4*)(Crow + (size_t)k*128);
    #pragma unroll
    for (int u = 0; u < 4; ++u){
      float y = Y[rq*4 + u][k];
      acc[u][0] += y*c.x; acc[u][1] += y*c.y; acc[u][2] += y*c.z; acc[u][3] += y*c.w;
    }
  }
  float4 b1v = *(const float4*)(W1b + cq*4);
  #pragma unroll
  for (int u = 0; u < 4; ++u){
    int e = n0 + rq*4 + u;
    if (e < NEV){
      float Bv = Bs[e];
      float4 o;
      o.x = acc[u][0] + Bv*b1v.x; o.y = acc[u][1] + Bv*b1v.y;
      o.z = acc[u][2] + Bv*b1v.z; o.w = acc[u][3] + Bv*b1v.w;
      *(float4*)(T + (size_t)e*DIM + cq*4) = o;
    }
  }
}

// ---------------- scatter to vertices: S2[v] += a*Xe[e] (into d_out) ----------------
__global__ __launch_bounds__(256) void scatter_vertex(
        const int* __restrict__ vertex, const int* __restrict__ edges,
        const float* __restrict__ alpha, const float* __restrict__ ws,
        float* __restrict__ S2){
  int i = blockIdx.x*2 + (threadIdx.x >> 7);
  int d = threadIdx.x & 127;
  int v = vertex[i]; int e = edges[i]; float a = alpha[i];
  const float* Xe = ws + T_OFF;
  float val = a * Xe[(size_t)e*DIM + d];
  atomicAdd(S2 + (size_t)v*DIM + d, val);
}

// ---------------- out = [A*X | S2 | X0] @ Ct + A*bA + Wb  (in-place over S2) ----------------
__global__ __launch_bounds__(256) void gemm_final(
        const float* __restrict__ X, const float* __restrict__ X0,
        const float* __restrict__ Wb, const float* __restrict__ ws,
        float* __restrict__ out){
  __shared__ float Y[32][72];
  const float* Ct = ws + CT_OFF;
  const float* Aa = ws + A_OFF;
  const float* bA = ws + BA_OFF;
  int n0 = blockIdx.x * 32;
  int tid = threadIdx.x;
  int rq = tid >> 5, cq = tid & 31;
  int lr = tid >> 3, lj = tid & 7;
  int gn = n0 + lr; if (gn >= NV) gn = NV - 1;
  float Ar = Aa[gn];
  float acc[4][4];
  #pragma unroll
  for (int u=0;u<4;++u){ acc[u][0]=0;acc[u][1]=0;acc[u][2]=0;acc[u][3]=0; }
  for (int ch = 0; ch < 6; ++ch){
    float4 v0, v1;
    {
      const float* src;
      if (ch < 2)      src = X   + (size_t)gn*DIM + (ch    )*64 + lj*8;
      else if (ch < 4) src = out + (size_t)gn*DIM + (ch - 2)*64 + lj*8;
      else             src = X0  + (size_t)gn*DIM + (ch - 4)*64 + lj*8;
      v0 = *(const float4*)(src);
      v1 = *(const float4*)(src + 4);
      if (ch < 2){
        v0.x*=Ar; v0.y*=Ar; v0.z*=Ar; v0.w*=Ar;
        v1.x*=Ar; v1.y*=Ar; v1.z*=Ar; v1.w*=Ar;
      }
    }
    __syncthreads();
    *(float4*)(&Y[lr][lj*8])     = v0;
    *(float4*)(&Y[lr][lj*8 + 4]) = v1;
    __syncthreads();
    const float* Crow = Ct + (size_t)(ch*64)*128 + cq*4;
    #pragma unroll 8
    for (int k = 0; k < 64; ++k){
      float4 c = *(const float4*)(Crow + (size_t)k*128);
      #pragma unroll
      for (int u = 0; u < 4; ++u){
        float y = Y[rq*4 + u][k];
        acc[u][0] += y*c.x; acc[u][1] += y*c.y; acc[u][2] += y*c.z; acc[u][3] += y*c.w;
      }
    }
  }
  float4 vbA = *(const float4*)(bA + cq*4);
  float4 vbC = *(const float4*)(Wb + cq*4);
  #pragma unroll
  for (int u = 0; u < 4; ++u){
    int n = n0 + rq*4 + u;
    if (n < NV){
      float Av = Aa[n];
      float4 o;
      o.x = acc[u][0] + Av*vbA.x + vbC.x;
      o.y = acc[u][1] + Av*vbA.y + vbC.y;
      o.z = acc[u][2] + Av*vbA.z + vbC.z;
      o.w = acc[u][3] + Av*vbA.w + vbC.w;
      *(float4*)(out + (size_t)n*DIM + cq*4) = o;
    }
  }
}

extern "C" void kernel_launch(void* const* d_in, const int* in_sizes, int n_in,
                              void* d_out, int out_size, void* d_ws, size_t ws_size,
                              hipStream_t stream){
  const float* X    = (const float*)d_in[0];
  const int*  vertex= (const int*)  d_in[1];
  const int*  edges = (const int*)  d_in[2];
  const float* X0   = (const float*)d_in[3];
  const float* alpha= (const float*)d_in[4];
  const float* W1w  = (const float*)d_in[5];
  const float* W1b  = (const float*)d_in[6];
  const float* W2w  = (const float*)d_in[7];
  const float* W2b  = (const float*)d_in[8];
  const float* Ww   = (const float*)d_in[9];
  const float* Wb   = (const float*)d_in[10];
  float* out = (float*)d_out;
  float* ws  = (float*)d_ws;

  hipMemsetAsync(ws + A_OFF, 0, (size_t)NV * 4, stream);
  hipMemsetAsync(ws + B_OFF, 0, (size_t)NEV * 4, stream);
  hipMemsetAsync(ws + T_OFF, 0, (size_t)NEV * DIM * 4, stream);
  hipMemsetAsync(out,        0, (size_t)NV  * DIM * 4, stream);

  prep_weights <<<513, 128, 0, stream>>>(W1w, W2w, W2b, Ww, ws);
  scatter_edges<<<NNZV/2, 256, 0, stream>>>(X, vertex, edges, alpha, ws);
  gemm_xe      <<<(NEV + 31)/32, 256, 0, stream>>>(W1b, ws);
  scatter_vertex<<<NNZV/2, 256, 0, stream>>>(vertex, edges, alpha, ws, out);
  gemm_final   <<<(NV + 31)/32, 256, 0, stream>>>(X, X0, Wb, ws, out);
}

// Round 2
// 461.846 us; speedup vs baseline: 1.5398x; 1.5398x over previous
//
#include <hip/hip_runtime.h>

#define NV   50000
#define NEV  10000
#define NNZV 600000
#define DIM  128

// workspace layout (float offsets)
#define CT_OFF   0          // 384*128 combined final weights, [k][o]
#define WT1_OFF  49152      // 128*128 W1 transposed, [k][o]
#define BA_OFF   65536      // 128 (A-scaled bias), pad to 256
#define A_OFF    65792      // 50048: per-vertex alpha sum
#define B_OFF    115840     // 10048: per-edge alpha sum
#define T_OFF    125888     // NE*128: T, then Xe in-place
#define CNTE_OFF 1405888    // int, NE+pad
#define OFFE_OFF 1415904    // int, NE+1
#define CURE_OFF 1425920    // int
#define CNTV_OFF 1435936    // int, NV+pad
#define OFFV_OFF 1485952    // int, NV+1
#define CURV_OFF 1535968    // int
#define VE_OFF   1585984    // int 600000: vertex ids grouped by edge
#define AE_OFF   2185984    // float 600000: alphas grouped by edge
#define EV_OFF   2785984    // int 600000: edge ids grouped by vertex
#define AV_OFF   3385984    // float 600000: alphas grouped by vertex
// total 3985984 floats ~ 15.9 MB

// ---------------- weight preparation (tiny) ----------------
__global__ __launch_bounds__(128) void prep_weights(
        const float* __restrict__ W1w, const float* __restrict__ W2w,
        const float* __restrict__ W2b, const float* __restrict__ Ww,
        float* __restrict__ ws){
  int b = blockIdx.x, o = threadIdx.x;
  if (b < 384){
    float s;
    if (b < 256){
      float acc = 0.f;
      for (int m = 0; m < 128; ++m) acc += Ww[o*128 + m] * W2w[m*256 + b];
      s = 0.5f * acc;
    } else {
      s = 0.5f * Ww[o*128 + (b - 256)];
    }
    ws[CT_OFF + b*128 + o] = s;
  } else if (b < 512){
    int k = b - 384;
    ws[WT1_OFF + k*128 + o] = W1w[o*128 + k];
  } else {
    float acc = 0.f;
    for (int m = 0; m < 128; ++m) acc += Ww[o*128 + m] * W2b[m];
    ws[BA_OFF + o] = 0.5f * acc;
  }
}

// ---------------- histogram of edges/vertices ----------------
__global__ __launch_bounds__(256) void count_kernel(
        const int* __restrict__ vertex, const int* __restrict__ edges,
        int* __restrict__ cntE, int* __restrict__ cntV){
  int i = blockIdx.x*256 + threadIdx.x;
  if (i >= NNZV) return;
  atomicAdd(cntE + edges[i], 1);
  atomicAdd(cntV + vertex[i], 1);
}

// ---------------- two exclusive scans (block 0: edges, block 1: vertices) ----------------
__global__ __launch_bounds__(1024) void scan2(
        const int* __restrict__ cntE, int* __restrict__ offE, int* __restrict__ curE,
        const int* __restrict__ cntV, int* __restrict__ offV, int* __restrict__ curV){
  const int* cnt; int* off; int* cur; int n;
  if (blockIdx.x == 0){ cnt = cntE; off = offE; cur = curE; n = NEV; }
  else                { cnt = cntV; off = offV; cur = curV; n = NV;  }
  __shared__ int s[1024];
  int t = threadIdx.x;
  int C = (n + 1023) >> 10;
  int base = t * C;
  int loc = 0;
  for (int j = 0; j < C; ++j){
    int idx = base + j;
    if (idx < n) loc += cnt[idx];
  }
  s[t] = loc;
  __syncthreads();
  for (int d = 1; d < 1024; d <<= 1){
    int val = (t >= d) ? s[t - d] : 0;
    __syncthreads();
    s[t] += val;
    __syncthreads();
  }
  int running = s[t] - loc;           // exclusive start for this chunk
  for (int j = 0; j < C; ++j){
    int idx = base + j;
    if (idx < n){
      off[idx] = running;
      cur[idx] = running;
      running += cnt[idx];
    }
  }
  if (t == 1023) off[n] = s[1023];
}

// ---------------- fill permuted lists ----------------
__global__ __launch_bounds__(256) void fill_lists(
        const int* __restrict__ vertex, const int* __restrict__ edges,
        const float* __restrict__ alpha,
        int* __restrict__ curE, int* __restrict__ curV,
        int* __restrict__ vE, float* __restrict__ aE,
        int* __restrict__ eV, float* __restrict__ aV){
  int i = blockIdx.x*256 + threadIdx.x;
  if (i >= NNZV) return;
  int v = vertex[i], e = edges[i];
  float a = alpha[i];
  int pE = atomicAdd(curE + e, 1);
  vE[pE] = v; aE[pE] = a;
  int pV = atomicAdd(curV + v, 1);
  eV[pV] = e; aV[pV] = a;
}

// ---------------- per-edge reduce: T[e] = sum a*X[v], B[e] = sum a ----------------
__global__ __launch_bounds__(128) void edge_reduce(
        const float* __restrict__ X, const int* __restrict__ offE,
        const int* __restrict__ vE, const float* __restrict__ aE,
        float* __restrict__ T, float* __restrict__ B){
  int e = blockIdx.x, d = threadIdx.x;
  int s0 = offE[e], s1 = offE[e+1];
  __shared__ int   vs[128];
  __shared__ float as[128];
  float acc = 0.f, bacc = 0.f;
  for (int base = s0; base < s1; base += 128){
    int L = min(128, s1 - base);
    __syncthreads();
    if (d < L){ vs[d] = vE[base + d]; as[d] = aE[base + d]; }
    __syncthreads();
    for (int j = 0; j < L; ++j){
      float a = as[j];
      acc  += a * X[(size_t)vs[j]*DIM + d];
      bacc += a;
    }
  }
  T[(size_t)e*DIM + d] = acc;
  if (d == 0) B[e] = bacc;
}

// ---------------- Xe = T @ Wt1 + B*b1  (in-place over T) ----------------
__global__ __launch_bounds__(256) void gemm_xe(const float* __restrict__ W1b,
                                               float* __restrict__ ws){
  __shared__ float Y[32][136];
  float* T = ws + T_OFF;
  const float* Wt1 = ws + WT1_OFF;
  const float* Bs  = ws + B_OFF;
  int n0 = blockIdx.x * 32;
  int tid = threadIdx.x;
  {
    int lr = tid >> 3, lj = tid & 7;
    int gn = n0 + lr; if (gn >= NEV) gn = NEV - 1;
    const float* src = T + (size_t)gn*DIM + lj*16;
    #pragma unroll
    for (int q = 0; q < 4; ++q)
      *(float4*)(&Y[lr][lj*16 + q*4]) = *(const float4*)(src + q*4);
  }
  __syncthreads();
  int rq = tid >> 5, cq = tid & 31;
  float acc[4][4];
  #pragma unroll
  for (int u=0;u<4;++u){ acc[u][0]=0;acc[u][1]=0;acc[u][2]=0;acc[u][3]=0; }
  const float* Crow = Wt1 + cq*4;
  #pragma unroll 4
  for (int k = 0; k < 128; ++k){
    float4 c = *(const float4*)(Crow + (size_t)k*128);
    #pragma unroll
    for (int u = 0; u < 4; ++u){
      float y = Y[rq*4 + u][k];
      acc[u][0] += y*c.x; acc[u][1] += y*c.y; acc[u][2] += y*c.z; acc[u][3] += y*c.w;
    }
  }
  float4 b1v = *(const float4*)(W1b + cq*4);
  #pragma unroll
  for (int u = 0; u < 4; ++u){
    int e = n0 + rq*4 + u;
    if (e < NEV){
      float Bv = Bs[e];
      float4 o;
      o.x = acc[u][0] + Bv*b1v.x; o.y = acc[u][1] + Bv*b1v.y;
      o.z = acc[u][2] + Bv*b1v.z; o.w = acc[u][3] + Bv*b1v.w;
      *(float4*)(T + (size_t)e*DIM + cq*4) = o;
    }
  }
}

// ---------------- per-vertex reduce: S2[v] = sum a*Xe[e] (into out), A[v] = sum a ----------------
__global__ __launch_bounds__(128) void vertex_reduce(
        const float* __restrict__ Xe, const int* __restrict__ offV,
        const int* __restrict__ eV, const float* __restrict__ aV,
        float* __restrict__ S2, float* __restrict__ A){
  int v = blockIdx.x, d = threadIdx.x;
  int s0 = offV[v], s1 = offV[v+1];
  __shared__ int   es[128];
  __shared__ float as[128];
  float acc = 0.f, aacc = 0.f;
  for (int base = s0; base < s1; base += 128){
    int L = min(128, s1 - base);
    __syncthreads();
    if (d < L){ es[d] = eV[base + d]; as[d] = aV[base + d]; }
    __syncthreads();
    for (int j = 0; j < L; ++j){
      float a = as[j];
      acc  += a * Xe[(size_t)es[j]*DIM + d];
      aacc += a;
    }
  }
  S2[(size_t)v*DIM + d] = acc;
  if (d == 0) A[v] = aacc;
}

// ---------------- out = [A*X | S2 | X0] @ Ct + A*bA + Wb  (in-place over S2) ----------------
__global__ __launch_bounds__(256) void gemm_final(
        const float* __restrict__ X, const float* __restrict__ X0,
        const float* __restrict__ Wb, const float* __restrict__ ws,
        float* __restrict__ out){
  __shared__ float Y[32][72];
  const float* Ct = ws + CT_OFF;
  const float* Aa = ws + A_OFF;
  const float* bA = ws + BA_OFF;
  int n0 = blockIdx.x * 32;
  int tid = threadIdx.x;
  int rq = tid >> 5, cq = tid & 31;
  int lr = tid >> 3, lj = tid & 7;
  int gn = n0 + lr; if (gn >= NV) gn = NV - 1;
  float Ar = Aa[gn];
  float acc[4][4];
  #pragma unroll
  for (int u=0;u<4;++u){ acc[u][0]=0;acc[u][1]=0;acc[u][2]=0;acc[u][3]=0; }
  for (int ch = 0; ch < 6; ++ch){
    float4 v0, v1;
    {
      const float* src;
      if (ch < 2)      src = X   + (size_t)gn*DIM + (ch    )*64 + lj*8;
      else if (ch < 4) src = out + (size_t)gn*DIM + (ch - 2)*64 + lj*8;
      else             src = X0  + (size_t)gn*DIM + (ch - 4)*64 + lj*8;
      v0 = *(const float4*)(src);
      v1 = *(const float4*)(src + 4);
      if (ch < 2){
        v0.x*=Ar; v0.y*=Ar; v0.z*=Ar; v0.w*=Ar;
        v1.x*=Ar; v1.y*=Ar; v1.z*=Ar; v1.w*=Ar;
      }
    }
    __syncthreads();
    *(float4*)(&Y[lr][lj*8])     = v0;
    *(float4*)(&Y[lr][lj*8 + 4]) = v1;
    __syncthreads();
    const float* Crow = Ct + (size_t)(ch*64)*128 + cq*4;
    #pragma unroll 8
    for (int k = 0; k < 64; ++k){
      float4 c = *(const float4*)(Crow + (size_t)k*128);
      #pragma unroll
      for (int u = 0; u < 4; ++u){
        float y = Y[rq*4 + u][k];
        acc[u][0] += y*c.x; acc[u][1] += y*c.y; acc[u][2] += y*c.z; acc[u][3] += y*c.w;
      }
    }
  }
  float4 vbA = *(const float4*)(bA + cq*4);
  float4 vbC = *(const float4*)(Wb + cq*4);
  #pragma unroll
  for (int u = 0; u < 4; ++u){
    int n = n0 + rq*4 + u;
    if (n < NV){
      float Av = Aa[n];
      float4 o;
      o.x = acc[u][0] + Av*vbA.x + vbC.x;
      o.y = acc[u][1] + Av*vbA.y + vbC.y;
      o.z = acc[u][2] + Av*vbA.z + vbC.z;
      o.w = acc[u][3] + Av*vbA.w + vbC.w;
      *(float4*)(out + (size_t)n*DIM + cq*4) = o;
    }
  }
}

extern "C" void kernel_launch(void* const* d_in, const int* in_sizes, int n_in,
                              void* d_out, int out_size, void* d_ws, size_t ws_size,
                              hipStream_t stream){
  const float* X    = (const float*)d_in[0];
  const int*  vertex= (const int*)  d_in[1];
  const int*  edges = (const int*)  d_in[2];
  const float* X0   = (const float*)d_in[3];
  const float* alpha= (const float*)d_in[4];
  const float* W1w  = (const float*)d_in[5];
  const float* W1b  = (const float*)d_in[6];
  const float* W2w  = (const float*)d_in[7];
  const float* W2b  = (const float*)d_in[8];
  const float* Ww   = (const float*)d_in[9];
  const float* Wb   = (const float*)d_in[10];
  float* out = (float*)d_out;
  float* ws  = (float*)d_ws;

  int* cntE = (int*)(ws + CNTE_OFF);
  int* offE = (int*)(ws + OFFE_OFF);
  int* curE = (int*)(ws + CURE_OFF);
  int* cntV = (int*)(ws + CNTV_OFF);
  int* offV = (int*)(ws + OFFV_OFF);
  int* curV = (int*)(ws + CURV_OFF);
  int*   vE = (int*)(ws + VE_OFF);
  float* aE =        ws + AE_OFF;
  int*   eV = (int*)(ws + EV_OFF);
  float* aV =        ws + AV_OFF;

  hipMemsetAsync(cntE, 0, 10016u * 4, stream);
  hipMemsetAsync(cntV, 0, 50016u * 4, stream);

  prep_weights <<<513, 128, 0, stream>>>(W1w, W2w, W2b, Ww, ws);
  count_kernel <<<(NNZV + 255)/256, 256, 0, stream>>>(vertex, edges, cntE, cntV);
  scan2        <<<2, 1024, 0, stream>>>(cntE, offE, curE, cntV, offV, curV);
  fill_lists   <<<(NNZV + 255)/256, 256, 0, stream>>>(vertex, edges, alpha,
                                                      curE, curV, vE, aE, eV, aV);
  edge_reduce  <<<NEV, 128, 0, stream>>>(X, offE, vE, aE, ws + T_OFF, ws + B_OFF);
  gemm_xe      <<<(NEV + 31)/32, 256, 0, stream>>>(W1b, ws);
  vertex_reduce<<<NV, 128, 0, stream>>>(ws + T_OFF, offV, eV, aV, out, ws + A_OFF);
  gemm_final   <<<(NV + 31)/32, 256, 0, stream>>>(X, X0, Wb, ws, out);
}

// Round 3
// 366.212 us; speedup vs baseline: 1.9419x; 1.2611x over previous
//
#include <hip/hip_runtime.h>

#define NV   50000
#define NEV  10000
#define NNZV 600000
#define DIM  128

#define NBE  40     // ceil(NEV/256)
#define NBV  196    // ceil(NV/256)

// workspace layout (float offsets)
#define CT_OFF    0          // 384*128 combined final weights, [k][o]
#define WT1_OFF   49152      // 128*128 W1 transposed, [k][o]
#define BA_OFF    65536      // 128 (A-scaled bias), pad to 256
#define A_OFF     65792      // 50048: per-vertex alpha sum
#define B_OFF     115840     // 10048: per-edge alpha sum
#define T_OFF     125888     // NE*128: T, then Xe in-place
#define CNTE_OFF  1405888    // int 10016
#define OFFE_OFF  1415904    // int 10016
#define CURE_OFF  1425920    // int 10016
#define CNTV_OFF  1435936    // int 50016
#define OFFV_OFF  1485952    // int 50016
#define CURV_OFF  1535968    // int 50016
#define BSUM_OFF  1585984    // int 256
#define BBASE_OFF 1586240    // int 256
#define VAE_OFF   1586496    // int2 600000 (vertex id, alpha bits) grouped by edge
#define VAV_OFF   2786496    // int2 600000 (edge id, alpha bits) grouped by vertex
// total 3986496 floats ~ 15.9 MB

// ---------------- weight preparation (tiny) ----------------
__global__ __launch_bounds__(128) void prep_weights(
        const float* __restrict__ W1w, const float* __restrict__ W2w,
        const float* __restrict__ W2b, const float* __restrict__ Ww,
        float* __restrict__ ws){
  int b = blockIdx.x, o = threadIdx.x;
  if (b < 384){
    float s;
    if (b < 256){
      float acc = 0.f;
      for (int m = 0; m < 128; ++m) acc += Ww[o*128 + m] * W2w[m*256 + b];
      s = 0.5f * acc;
    } else {
      s = 0.5f * Ww[o*128 + (b - 256)];
    }
    ws[CT_OFF + b*128 + o] = s;
  } else if (b < 512){
    int k = b - 384;
    ws[WT1_OFF + k*128 + o] = W1w[o*128 + k];
  } else {
    float acc = 0.f;
    for (int m = 0; m < 128; ++m) acc += Ww[o*128 + m] * W2b[m];
    ws[BA_OFF + o] = 0.5f * acc;
  }
}

// ---------------- histogram of edges/vertices ----------------
__global__ __launch_bounds__(256) void count_kernel(
        const int* __restrict__ vertex, const int* __restrict__ edges,
        int* __restrict__ cntE, int* __restrict__ cntV){
  int i = blockIdx.x*256 + threadIdx.x;
  if (i >= NNZV) return;
  atomicAdd(cntE + edges[i], 1);
  atomicAdd(cntV + vertex[i], 1);
}

// ---------------- hierarchical scan: pass 1 (block sums) ----------------
__global__ __launch_bounds__(256) void scan_partial(
        const int* __restrict__ cntE, const int* __restrict__ cntV,
        int* __restrict__ bsum){
  int bid = blockIdx.x, t = threadIdx.x;
  const int* cnt; int n, li;
  if (bid < NBE){ cnt = cntE; n = NEV; li = bid*256 + t; }
  else          { cnt = cntV; n = NV;  li = (bid - NBE)*256 + t; }
  int c = (li < n) ? cnt[li] : 0;
  __shared__ int s[256];
  s[t] = c; __syncthreads();
  for (int d = 128; d > 0; d >>= 1){
    if (t < d) s[t] += s[t + d];
    __syncthreads();
  }
  if (t == 0) bsum[bid] = s[0];
}

// ---------------- pass 2: scan the block sums (both segments) ----------------
__global__ __launch_bounds__(256) void scan_base(
        const int* __restrict__ bsum, int* __restrict__ bbase,
        int* __restrict__ offE, int* __restrict__ offV){
  __shared__ int s[256];
  int t = threadIdx.x;
  int v = (t < NBE) ? bsum[t] : 0;
  s[t] = v; __syncthreads();
  for (int d = 1; d < 256; d <<= 1){
    int x = (t >= d) ? s[t - d] : 0;
    __syncthreads(); s[t] += x; __syncthreads();
  }
  if (t < NBE) bbase[t] = s[t] - v;
  __syncthreads();
  int v2 = (t < NBV) ? bsum[NBE + t] : 0;
  s[t] = v2; __syncthreads();
  for (int d = 1; d < 256; d <<= 1){
    int x = (t >= d) ? s[t - d] : 0;
    __syncthreads(); s[t] += x; __syncthreads();
  }
  if (t < NBV) bbase[NBE + t] = s[t] - v2;
  if (t == 0){ offE[NEV] = NNZV; offV[NV] = NNZV; }
}

// ---------------- pass 3: per-block exclusive scan + base ----------------
__global__ __launch_bounds__(256) void scan_apply(
        const int* __restrict__ cntE, const int* __restrict__ cntV,
        const int* __restrict__ bbase,
        int* __restrict__ offE, int* __restrict__ curE,
        int* __restrict__ offV, int* __restrict__ curV){
  int bid = blockIdx.x, t = threadIdx.x;
  const int* cnt; int n, li; int* off; int* cur;
  if (bid < NBE){ cnt = cntE; n = NEV; li = bid*256 + t; off = offE; cur = curE; }
  else          { cnt = cntV; n = NV;  li = (bid - NBE)*256 + t; off = offV; cur = curV; }
  int c = (li < n) ? cnt[li] : 0;
  __shared__ int s[256];
  s[t] = c; __syncthreads();
  for (int d = 1; d < 256; d <<= 1){
    int x = (t >= d) ? s[t - d] : 0;
    __syncthreads(); s[t] += x; __syncthreads();
  }
  int excl = s[t] - c + bbase[bid];
  if (li < n){ off[li] = excl; cur[li] = excl; }
}

// ---------------- fill permuted lists (packed int2) ----------------
__global__ __launch_bounds__(256) void fill_lists(
        const int* __restrict__ vertex, const int* __restrict__ edges,
        const float* __restrict__ alpha,
        int* __restrict__ curE, int* __restrict__ curV,
        int2* __restrict__ vaE, int2* __restrict__ vaV){
  int i = blockIdx.x*256 + threadIdx.x;
  if (i >= NNZV) return;
  int v = vertex[i], e = edges[i];
  int ab = __float_as_int(alpha[i]);
  int pE = atomicAdd(curE + e, 1);
  vaE[pE] = make_int2(v, ab);
  int pV = atomicAdd(curV + v, 1);
  vaV[pV] = make_int2(e, ab);
}

// ---------------- per-edge reduce: T[e] = sum a*X[v], B[e] = sum a ----------------
__global__ __launch_bounds__(128) void edge_reduce(
        const float* __restrict__ X, const int* __restrict__ offE,
        const int2* __restrict__ vaE,
        float* __restrict__ T, float* __restrict__ B){
  int e = blockIdx.x, d = threadIdx.x;
  int s0 = offE[e], s1 = offE[e+1];
  __shared__ int   vs[128];
  __shared__ float as[128];
  float acc = 0.f, bacc = 0.f;
  for (int base = s0; base < s1; base += 128){
    int L = min(128, s1 - base);
    __syncthreads();
    if (d < L){ int2 p = vaE[base + d]; vs[d] = p.x; as[d] = __int_as_float(p.y); }
    __syncthreads();
    for (int j = 0; j < L; ++j){
      float a = as[j];
      acc  += a * X[(size_t)vs[j]*DIM + d];
      bacc += a;
    }
  }
  T[(size_t)e*DIM + d] = acc;
  if (d == 0) B[e] = bacc;
}

// ---------------- Xe = T @ Wt1 + B*b1  (in-place over T) ----------------
__global__ __launch_bounds__(256) void gemm_xe(const float* __restrict__ W1b,
                                               float* __restrict__ ws){
  __shared__ float Y[32][136];
  float* T = ws + T_OFF;
  const float* Wt1 = ws + WT1_OFF;
  const float* Bs  = ws + B_OFF;
  int n0 = blockIdx.x * 32;
  int tid = threadIdx.x;
  {
    int lr = tid >> 3, lj = tid & 7;
    int gn = n0 + lr; if (gn >= NEV) gn = NEV - 1;
    const float* src = T + (size_t)gn*DIM + lj*16;
    #pragma unroll
    for (int q = 0; q < 4; ++q)
      *(float4*)(&Y[lr][lj*16 + q*4]) = *(const float4*)(src + q*4);
  }
  __syncthreads();
  int rq = tid >> 5, cq = tid & 31;
  float acc[4][4];
  #pragma unroll
  for (int u=0;u<4;++u){ acc[u][0]=0;acc[u][1]=0;acc[u][2]=0;acc[u][3]=0; }
  const float* Crow = Wt1 + cq*4;
  #pragma unroll 4
  for (int k = 0; k < 128; ++k){
    float4 c = *(const float4*)(Crow + (size_t)k*128);
    #pragma unroll
    for (int u = 0; u < 4; ++u){
      float y = Y[rq*4 + u][k];
      acc[u][0] += y*c.x; acc[u][1] += y*c.y; acc[u][2] += y*c.z; acc[u][3] += y*c.w;
    }
  }
  float4 b1v = *(const float4*)(W1b + cq*4);
  #pragma unroll
  for (int u = 0; u < 4; ++u){
    int e = n0 + rq*4 + u;
    if (e < NEV){
      float Bv = Bs[e];
      float4 o;
      o.x = acc[u][0] + Bv*b1v.x; o.y = acc[u][1] + Bv*b1v.y;
      o.z = acc[u][2] + Bv*b1v.z; o.w = acc[u][3] + Bv*b1v.w;
      *(float4*)(T + (size_t)e*DIM + cq*4) = o;
    }
  }
}

// ---------------- per-vertex reduce: S2[v] = sum a*Xe[e] (into out), A[v] = sum a ----------------
__global__ __launch_bounds__(128) void vertex_reduce(
        const float* __restrict__ Xe, const int* __restrict__ offV,
        const int2* __restrict__ vaV,
        float* __restrict__ S2, float* __restrict__ A){
  int v = blockIdx.x, d = threadIdx.x;
  int s0 = offV[v], s1 = offV[v+1];
  __shared__ int   es[128];
  __shared__ float as[128];
  float acc = 0.f, aacc = 0.f;
  for (int base = s0; base < s1; base += 128){
    int L = min(128, s1 - base);
    __syncthreads();
    if (d < L){ int2 p = vaV[base + d]; es[d] = p.x; as[d] = __int_as_float(p.y); }
    __syncthreads();
    for (int j = 0; j < L; ++j){
      float a = as[j];
      acc  += a * Xe[(size_t)es[j]*DIM + d];
      aacc += a;
    }
  }
  S2[(size_t)v*DIM + d] = acc;
  if (d == 0) A[v] = aacc;
}

// ---------------- out = [A*X | S2 | X0] @ Ct + A*bA + Wb  (in-place over S2) ----------------
__global__ __launch_bounds__(256) void gemm_final(
        const float* __restrict__ X, const float* __restrict__ X0,
        const float* __restrict__ Wb, const float* __restrict__ ws,
        float* __restrict__ out){
  __shared__ float Y[32][72];
  const float* Ct = ws + CT_OFF;
  const float* Aa = ws + A_OFF;
  const float* bA = ws + BA_OFF;
  int n0 = blockIdx.x * 32;
  int tid = threadIdx.x;
  int rq = tid >> 5, cq = tid & 31;
  int lr = tid >> 3, lj = tid & 7;
  int gn = n0 + lr; if (gn >= NV) gn = NV - 1;
  float Ar = Aa[gn];
  float acc[4][4];
  #pragma unroll
  for (int u=0;u<4;++u){ acc[u][0]=0;acc[u][1]=0;acc[u][2]=0;acc[u][3]=0; }
  for (int ch = 0; ch < 6; ++ch){
    float4 v0, v1;
    {
      const float* src;
      if (ch < 2)      src = X   + (size_t)gn*DIM + (ch    )*64 + lj*8;
      else if (ch < 4) src = out + (size_t)gn*DIM + (ch - 2)*64 + lj*8;
      else             src = X0  + (size_t)gn*DIM + (ch - 4)*64 + lj*8;
      v0 = *(const float4*)(src);
      v1 = *(const float4*)(src + 4);
      if (ch < 2){
        v0.x*=Ar; v0.y*=Ar; v0.z*=Ar; v0.w*=Ar;
        v1.x*=Ar; v1.y*=Ar; v1.z*=Ar; v1.w*=Ar;
      }
    }
    __syncthreads();
    *(float4*)(&Y[lr][lj*8])     = v0;
    *(float4*)(&Y[lr][lj*8 + 4]) = v1;
    __syncthreads();
    const float* Crow = Ct + (size_t)(ch*64)*128 + cq*4;
    #pragma unroll 8
    for (int k = 0; k < 64; ++k){
      float4 c = *(const float4*)(Crow + (size_t)k*128);
      #pragma unroll
      for (int u = 0; u < 4; ++u){
        float y = Y[rq*4 + u][k];
        acc[u][0] += y*c.x; acc[u][1] += y*c.y; acc[u][2] += y*c.z; acc[u][3] += y*c.w;
      }
    }
  }
  float4 vbA = *(const float4*)(bA + cq*4);
  float4 vbC = *(const float4*)(Wb + cq*4);
  #pragma unroll
  for (int u = 0; u < 4; ++u){
    int n = n0 + rq*4 + u;
    if (n < NV){
      float Av = Aa[n];
      float4 o;
      o.x = acc[u][0] + Av*vbA.x + vbC.x;
      o.y = acc[u][1] + Av*vbA.y + vbC.y;
      o.z = acc[u][2] + Av*vbA.z + vbC.z;
      o.w = acc[u][3] + Av*vbA.w + vbC.w;
      *(float4*)(out + (size_t)n*DIM + cq*4) = o;
    }
  }
}

extern "C" void kernel_launch(void* const* d_in, const int* in_sizes, int n_in,
                              void* d_out, int out_size, void* d_ws, size_t ws_size,
                              hipStream_t stream){
  const float* X    = (const float*)d_in[0];
  const int*  vertex= (const int*)  d_in[1];
  const int*  edges = (const int*)  d_in[2];
  const float* X0   = (const float*)d_in[3];
  const float* alpha= (const float*)d_in[4];
  const float* W1w  = (const float*)d_in[5];
  const float* W1b  = (const float*)d_in[6];
  const float* W2w  = (const float*)d_in[7];
  const float* W2b  = (const float*)d_in[8];
  const float* Ww   = (const float*)d_in[9];
  const float* Wb   = (const float*)d_in[10];
  float* out = (float*)d_out;
  float* ws  = (float*)d_ws;

  int* cntE  = (int*)(ws + CNTE_OFF);
  int* offE  = (int*)(ws + OFFE_OFF);
  int* curE  = (int*)(ws + CURE_OFF);
  int* cntV  = (int*)(ws + CNTV_OFF);
  int* offV  = (int*)(ws + OFFV_OFF);
  int* curV  = (int*)(ws + CURV_OFF);
  int* bsum  = (int*)(ws + BSUM_OFF);
  int* bbase = (int*)(ws + BBASE_OFF);
  int2* vaE  = (int2*)(ws + VAE_OFF);
  int2* vaV  = (int2*)(ws + VAV_OFF);

  hipMemsetAsync(cntE, 0, 10016u * 4, stream);
  hipMemsetAsync(cntV, 0, 50016u * 4, stream);

  prep_weights <<<513, 128, 0, stream>>>(W1w, W2w, W2b, Ww, ws);
  count_kernel <<<(NNZV + 255)/256, 256, 0, stream>>>(vertex, edges, cntE, cntV);
  scan_partial <<<NBE + NBV, 256, 0, stream>>>(cntE, cntV, bsum);
  scan_base    <<<1, 256, 0, stream>>>(bsum, bbase, offE, offV);
  scan_apply   <<<NBE + NBV, 256, 0, stream>>>(cntE, cntV, bbase, offE, curE, offV, curV);
  fill_lists   <<<(NNZV + 255)/256, 256, 0, stream>>>(vertex, edges, alpha,
                                                      curE, curV, vaE, vaV);
  edge_reduce  <<<NEV, 128, 0, stream>>>(X, offE, vaE, ws + T_OFF, ws + B_OFF);
  gemm_xe      <<<(NEV + 31)/32, 256, 0, stream>>>(W1b, ws);
  vertex_reduce<<<NV, 128, 0, stream>>>(ws + T_OFF, offV, vaV, out, ws + A_OFF);
  gemm_final   <<<(NV + 31)/32, 256, 0, stream>>>(X, X0, Wb, ws, out);
}

// Round 4
// 309.700 us; speedup vs baseline: 2.2962x; 1.1825x over previous
//
#include <hip/hip_runtime.h>

#define NV   50000
#define NEV  10000
#define NNZV 600000
#define DIM  128

#define NBE  40     // ceil(NEV/256)
#define NBV  196    // ceil(NV/256)

// workspace layout (float offsets)
#define CT_OFF    0          // Bpack: 49152 bf16 (24576 floats) — packed final weights
#define WT1_OFF   49152      // 128*128 W1 transposed, [k][o] fp32
#define BA_OFF    65536      // 128 (A-scaled bias), pad to 256
#define A_OFF     65792      // 50048: per-vertex alpha sum
#define B_OFF     115840     // 10048: per-edge alpha sum
#define T_OFF     125888     // NE*128: T, then Xe in-place
#define CNTE_OFF  1405888    // int 10016
#define OFFE_OFF  1415904    // int 10016
#define CURE_OFF  1425920    // int 10016
#define CNTV_OFF  1435936    // int 50016
#define OFFV_OFF  1485952    // int 50016
#define CURV_OFF  1535968    // int 50016
#define BSUM_OFF  1585984    // int 256
#define BBASE_OFF 1586240    // int 256
#define VAE_OFF   1586496    // int2 600000 (vertex id, alpha bits) grouped by edge
#define VAV_OFF   2786496    // int2 600000 (edge id, alpha bits) grouped by vertex
// total 3986496 floats ~ 15.9 MB

typedef __attribute__((ext_vector_type(8))) short bf16x8;
typedef __attribute__((ext_vector_type(4))) float f32x4;

__device__ __forceinline__ unsigned short f2bf(float x){
  unsigned u = __float_as_uint(x);
  u += 0x7fffu + ((u >> 16) & 1u);     // round-to-nearest-even
  return (unsigned short)(u >> 16);
}

// ---------------- weight preparation (tiny) ----------------
// Bpack: bf16 fragments of Ct (384x128) in per-lane MFMA order:
//   k -> (ks=k/32, g=(k>>3)&3, j=k&7), o -> (ct=o/16, lo=o&15)
//   Bpack[((ks*8+ct)*64 + g*16+lo)*8 + j]
__global__ __launch_bounds__(128) void prep_weights(
        const float* __restrict__ W1w, const float* __restrict__ W2w,
        const float* __restrict__ W2b, const float* __restrict__ Ww,
        float* __restrict__ ws){
  int b = blockIdx.x, o = threadIdx.x;
  if (b < 384){
    float s;
    if (b < 256){
      float acc = 0.f;
      for (int m = 0; m < 128; ++m) acc += Ww[o*128 + m] * W2w[m*256 + b];
      s = 0.5f * acc;
    } else {
      s = 0.5f * Ww[o*128 + (b - 256)];
    }
    int ks = b >> 5, g = (b >> 3) & 3, j = b & 7;
    int ct = o >> 4, lo = o & 15;
    unsigned short* Bp = (unsigned short*)(ws + CT_OFF);
    Bp[((size_t)((ks*8 + ct)*64 + g*16 + lo))*8 + j] = f2bf(s);
  } else if (b < 512){
    int k = b - 384;
    ws[WT1_OFF + k*128 + o] = W1w[o*128 + k];
  } else {
    float acc = 0.f;
    for (int m = 0; m < 128; ++m) acc += Ww[o*128 + m] * W2b[m];
    ws[BA_OFF + o] = 0.5f * acc;
  }
}

// ---------------- histogram of edges/vertices ----------------
__global__ __launch_bounds__(256) void count_kernel(
        const int* __restrict__ vertex, const int* __restrict__ edges,
        int* __restrict__ cntE, int* __restrict__ cntV){
  int i = blockIdx.x*256 + threadIdx.x;
  if (i >= NNZV) return;
  atomicAdd(cntE + edges[i], 1);
  atomicAdd(cntV + vertex[i], 1);
}

// ---------------- hierarchical scan: pass 1 (block sums) ----------------
__global__ __launch_bounds__(256) void scan_partial(
        const int* __restrict__ cntE, const int* __restrict__ cntV,
        int* __restrict__ bsum){
  int bid = blockIdx.x, t = threadIdx.x;
  const int* cnt; int n, li;
  if (bid < NBE){ cnt = cntE; n = NEV; li = bid*256 + t; }
  else          { cnt = cntV; n = NV;  li = (bid - NBE)*256 + t; }
  int c = (li < n) ? cnt[li] : 0;
  __shared__ int s[256];
  s[t] = c; __syncthreads();
  for (int d = 128; d > 0; d >>= 1){
    if (t < d) s[t] += s[t + d];
    __syncthreads();
  }
  if (t == 0) bsum[bid] = s[0];
}

// ---------------- pass 2: scan the block sums (both segments) ----------------
__global__ __launch_bounds__(256) void scan_base(
        const int* __restrict__ bsum, int* __restrict__ bbase,
        int* __restrict__ offE, int* __restrict__ offV){
  __shared__ int s[256];
  int t = threadIdx.x;
  int v = (t < NBE) ? bsum[t] : 0;
  s[t] = v; __syncthreads();
  for (int d = 1; d < 256; d <<= 1){
    int x = (t >= d) ? s[t - d] : 0;
    __syncthreads(); s[t] += x; __syncthreads();
  }
  if (t < NBE) bbase[t] = s[t] - v;
  __syncthreads();
  int v2 = (t < NBV) ? bsum[NBE + t] : 0;
  s[t] = v2; __syncthreads();
  for (int d = 1; d < 256; d <<= 1){
    int x = (t >= d) ? s[t - d] : 0;
    __syncthreads(); s[t] += x; __syncthreads();
  }
  if (t < NBV) bbase[NBE + t] = s[t] - v2;
  if (t == 0){ offE[NEV] = NNZV; offV[NV] = NNZV; }
}

// ---------------- pass 3: per-block exclusive scan + base ----------------
__global__ __launch_bounds__(256) void scan_apply(
        const int* __restrict__ cntE, const int* __restrict__ cntV,
        const int* __restrict__ bbase,
        int* __restrict__ offE, int* __restrict__ curE,
        int* __restrict__ offV, int* __restrict__ curV){
  int bid = blockIdx.x, t = threadIdx.x;
  const int* cnt; int n, li; int* off; int* cur;
  if (bid < NBE){ cnt = cntE; n = NEV; li = bid*256 + t; off = offE; cur = curE; }
  else          { cnt = cntV; n = NV;  li = (bid - NBE)*256 + t; off = offV; cur = curV; }
  int c = (li < n) ? cnt[li] : 0;
  __shared__ int s[256];
  s[t] = c; __syncthreads();
  for (int d = 1; d < 256; d <<= 1){
    int x = (t >= d) ? s[t - d] : 0;
    __syncthreads(); s[t] += x; __syncthreads();
  }
  int excl = s[t] - c + bbase[bid];
  if (li < n){ off[li] = excl; cur[li] = excl; }
}

// ---------------- fill permuted lists (packed int2) ----------------
__global__ __launch_bounds__(256) void fill_lists(
        const int* __restrict__ vertex, const int* __restrict__ edges,
        const float* __restrict__ alpha,
        int* __restrict__ curE, int* __restrict__ curV,
        int2* __restrict__ vaE, int2* __restrict__ vaV){
  int i = blockIdx.x*256 + threadIdx.x;
  if (i >= NNZV) return;
  int v = vertex[i], e = edges[i];
  int ab = __float_as_int(alpha[i]);
  int pE = atomicAdd(curE + e, 1);
  vaE[pE] = make_int2(v, ab);
  int pV = atomicAdd(curV + v, 1);
  vaV[pV] = make_int2(e, ab);
}

// ---------------- per-edge reduce: T[e] = sum a*X[v], B[e] = sum a ----------------
__global__ __launch_bounds__(128) void edge_reduce(
        const float* __restrict__ X, const int* __restrict__ offE,
        const int2* __restrict__ vaE,
        float* __restrict__ T, float* __restrict__ B){
  int e = blockIdx.x, d = threadIdx.x;
  int s0 = offE[e], s1 = offE[e+1];
  __shared__ int   vs[128];
  __shared__ float as[128];
  float acc = 0.f, bacc = 0.f;
  for (int base = s0; base < s1; base += 128){
    int L = min(128, s1 - base);
    __syncthreads();
    if (d < L){ int2 p = vaE[base + d]; vs[d] = p.x; as[d] = __int_as_float(p.y); }
    __syncthreads();
    for (int j = 0; j < L; ++j){
      float a = as[j];
      acc  += a * X[(size_t)vs[j]*DIM + d];
      bacc += a;
    }
  }
  T[(size_t)e*DIM + d] = acc;
  if (d == 0) B[e] = bacc;
}

// ---------------- Xe = T @ Wt1 + B*b1  (in-place over T) ----------------
__global__ __launch_bounds__(256) void gemm_xe(const float* __restrict__ W1b,
                                               float* __restrict__ ws){
  __shared__ float Y[32][136];
  float* T = ws + T_OFF;
  const float* Wt1 = ws + WT1_OFF;
  const float* Bs  = ws + B_OFF;
  int n0 = blockIdx.x * 32;
  int tid = threadIdx.x;
  {
    int lr = tid >> 3, lj = tid & 7;
    int gn = n0 + lr; if (gn >= NEV) gn = NEV - 1;
    const float* src = T + (size_t)gn*DIM + lj*16;
    #pragma unroll
    for (int q = 0; q < 4; ++q)
      *(float4*)(&Y[lr][lj*16 + q*4]) = *(const float4*)(src + q*4);
  }
  __syncthreads();
  int rq = tid >> 5, cq = tid & 31;
  float acc[4][4];
  #pragma unroll
  for (int u=0;u<4;++u){ acc[u][0]=0;acc[u][1]=0;acc[u][2]=0;acc[u][3]=0; }
  const float* Crow = Wt1 + cq*4;
  #pragma unroll 4
  for (int k = 0; k < 128; ++k){
    float4 c = *(const float4*)(Crow + (size_t)k*128);
    #pragma unroll
    for (int u = 0; u < 4; ++u){
      float y = Y[rq*4 + u][k];
      acc[u][0] += y*c.x; acc[u][1] += y*c.y; acc[u][2] += y*c.z; acc[u][3] += y*c.w;
    }
  }
  float4 b1v = *(const float4*)(W1b + cq*4);
  #pragma unroll
  for (int u = 0; u < 4; ++u){
    int e = n0 + rq*4 + u;
    if (e < NEV){
      float Bv = Bs[e];
      float4 o;
      o.x = acc[u][0] + Bv*b1v.x; o.y = acc[u][1] + Bv*b1v.y;
      o.z = acc[u][2] + Bv*b1v.z; o.w = acc[u][3] + Bv*b1v.w;
      *(float4*)(T + (size_t)e*DIM + cq*4) = o;
    }
  }
}

// ---------------- per-vertex reduce: S2[v] = sum a*Xe[e] (into out), A[v] = sum a ----------------
__global__ __launch_bounds__(128) void vertex_reduce(
        const float* __restrict__ Xe, const int* __restrict__ offV,
        const int2* __restrict__ vaV,
        float* __restrict__ S2, float* __restrict__ A){
  int v = blockIdx.x, d = threadIdx.x;
  int s0 = offV[v], s1 = offV[v+1];
  __shared__ int   es[128];
  __shared__ float as[128];
  float acc = 0.f, aacc = 0.f;
  for (int base = s0; base < s1; base += 128){
    int L = min(128, s1 - base);
    __syncthreads();
    if (d < L){ int2 p = vaV[base + d]; es[d] = p.x; as[d] = __int_as_float(p.y); }
    __syncthreads();
    for (int j = 0; j < L; ++j){
      float a = as[j];
      acc  += a * Xe[(size_t)es[j]*DIM + d];
      aacc += a;
    }
  }
  S2[(size_t)v*DIM + d] = acc;
  if (d == 0) A[v] = aacc;
}

// ---------------- out = [A*X | S2 | X0] @ Ct + A*bA + Wb  via bf16 MFMA ----------------
#define LDS_STRIDE 392   // shorts per row: 384 + 8 pad -> 784B, 16B aligned, 4-bank rotation

__global__ __launch_bounds__(256) void gemm_final_mfma(
        const float* __restrict__ X, const float* __restrict__ X0,
        const float* __restrict__ Wb, const float* __restrict__ ws,
        float* __restrict__ out){
  __shared__ unsigned short At[64 * LDS_STRIDE];
  __shared__ float ArS[64];
  const float* Aa = ws + A_OFF;
  const float* bA = ws + BA_OFF;
  const unsigned short* Bpack = (const unsigned short*)(ws + CT_OFF);
  int r0 = blockIdx.x * 64;
  int t = threadIdx.x;
  if (t < 64){
    int gn = r0 + t; if (gn >= NV) gn = NV - 1;
    ArS[t] = Aa[gn];
  }
  __syncthreads();
  // stage A-tile (64 x 384) as bf16: [Ar*X | S2 | X0]
  #pragma unroll
  for (int seg = 0; seg < 3; ++seg){
    const float* src = (seg == 0) ? X : (seg == 1) ? out : X0;
    #pragma unroll
    for (int i = 0; i < 8; ++i){
      int idx = t + i*256;              // 0..2047 (2048 float4 = 64x128 f32)
      int row = idx >> 5;               // 32 float4 per row
      int c4  = idx & 31;
      int gn = r0 + row; if (gn >= NV) gn = NV - 1;
      float4 v = *(const float4*)(src + (size_t)gn*DIM + c4*4);
      if (seg == 0){
        float Ar = ArS[row];
        v.x *= Ar; v.y *= Ar; v.z *= Ar; v.w *= Ar;
      }
      ushort4 h;
      h.x = f2bf(v.x); h.y = f2bf(v.y); h.z = f2bf(v.z); h.w = f2bf(v.w);
      *(ushort4*)(&At[row*LDS_STRIDE + seg*128 + c4*4]) = h;
    }
  }
  __syncthreads();

  int w = t >> 6, l = t & 63;
  int m0 = w * 16;                       // wave's 16-row slice of the 64-row tile
  int lr = l & 15, lg = l >> 4;
  f32x4 acc[8];
  #pragma unroll
  for (int ct = 0; ct < 8; ++ct) acc[ct] = (f32x4){0.f,0.f,0.f,0.f};

  const unsigned short* arow = &At[(m0 + lr)*LDS_STRIDE + lg*8];
  for (int ks = 0; ks < 12; ++ks){
    bf16x8 af = *(const bf16x8*)(arow + ks*32);
    const bf16x8* bp = (const bf16x8*)(Bpack) + (size_t)ks*8*64 + l;
    #pragma unroll
    for (int ct = 0; ct < 8; ++ct){
      bf16x8 bf = bp[ct*64];
      acc[ct] = __builtin_amdgcn_mfma_f32_16x16x32_bf16(af, bf, acc[ct], 0, 0, 0);
    }
  }

  // epilogue: D[m=(l>>4)*4+r][n=ct*16+(l&15)] (m89-verified C/D mapping)
  #pragma unroll
  for (int ct = 0; ct < 8; ++ct){
    int o = ct*16 + lr;
    float ba = bA[o], wb = Wb[o];
    #pragma unroll
    for (int r = 0; r < 4; ++r){
      int lrow = m0 + lg*4 + r;
      int row = r0 + lrow;
      if (row < NV){
        float Av = ArS[lrow];
        out[(size_t)row*DIM + o] = acc[ct][r] + Av*ba + wb;
      }
    }
  }
}

extern "C" void kernel_launch(void* const* d_in, const int* in_sizes, int n_in,
                              void* d_out, int out_size, void* d_ws, size_t ws_size,
                              hipStream_t stream){
  const float* X    = (const float*)d_in[0];
  const int*  vertex= (const int*)  d_in[1];
  const int*  edges = (const int*)  d_in[2];
  const float* X0   = (const float*)d_in[3];
  const float* alpha= (const float*)d_in[4];
  const float* W1w  = (const float*)d_in[5];
  const float* W1b  = (const float*)d_in[6];
  const float* W2w  = (const float*)d_in[7];
  const float* W2b  = (const float*)d_in[8];
  const float* Ww   = (const float*)d_in[9];
  const float* Wb   = (const float*)d_in[10];
  float* out = (float*)d_out;
  float* ws  = (float*)d_ws;

  int* cntE  = (int*)(ws + CNTE_OFF);
  int* offE  = (int*)(ws + OFFE_OFF);
  int* curE  = (int*)(ws + CURE_OFF);
  int* cntV  = (int*)(ws + CNTV_OFF);
  int* offV  = (int*)(ws + OFFV_OFF);
  int* curV  = (int*)(ws + CURV_OFF);
  int* bsum  = (int*)(ws + BSUM_OFF);
  int* bbase = (int*)(ws + BBASE_OFF);
  int2* vaE  = (int2*)(ws + VAE_OFF);
  int2* vaV  = (int2*)(ws + VAV_OFF);

  hipMemsetAsync(cntE, 0, 10016u * 4, stream);
  hipMemsetAsync(cntV, 0, 50016u * 4, stream);

  prep_weights <<<513, 128, 0, stream>>>(W1w, W2w, W2b, Ww, ws);
  count_kernel <<<(NNZV + 255)/256, 256, 0, stream>>>(vertex, edges, cntE, cntV);
  scan_partial <<<NBE + NBV, 256, 0, stream>>>(cntE, cntV, bsum);
  scan_base    <<<1, 256, 0, stream>>>(bsum, bbase, offE, offV);
  scan_apply   <<<NBE + NBV, 256, 0, stream>>>(cntE, cntV, bbase, offE, curE, offV, curV);
  fill_lists   <<<(NNZV + 255)/256, 256, 0, stream>>>(vertex, edges, alpha,
                                                      curE, curV, vaE, vaV);
  edge_reduce  <<<NEV, 128, 0, stream>>>(X, offE, vaE, ws + T_OFF, ws + B_OFF);
  gemm_xe      <<<(NEV + 31)/32, 256, 0, stream>>>(W1b, ws);
  vertex_reduce<<<NV, 128, 0, stream>>>(ws + T_OFF, offV, vaV, out, ws + A_OFF);
  gemm_final_mfma<<<(NV + 63)/64, 256, 0, stream>>>(X, X0, Wb, ws, out);
}

// Round 6
// 297.531 us; speedup vs baseline: 2.3901x; 1.0409x over previous
//
#include <hip/hip_runtime.h>

#define NV   50000
#define NEV  10000
#define NNZV 600000
#define DIM  128

#define NBE  40     // ceil(NEV/256)
#define NBV  196    // ceil(NV/256)

// workspace layout (float offsets) — total 3,401,920 floats = 13.6 MB (< proven 15.9 MB)
#define BPACK_OFF 0        // 24576: bf16 384x128 packed final weights
#define WT1_OFF   24576    // 16384: W1^T fp32 [k][o]
#define BA_OFF    40960    // 256
#define A_OFF     41216    // 50048: per-vertex alpha sum
#define B_OFF     91264    // 10048: per-edge alpha sum
#define T_OFF     101312   // 1280000: f32 T (edge features pre-GEMM)
#define XEBF_OFF  1381312  // 640000 floats = 1.28M ushort: bf16 Xe
#define CNTE_OFF  2021312  // int 10016
#define OFFE_OFF  2031328  // int 10016
#define CURE_OFF  2041344  // int 10016
#define CNTV_OFF  2051360  // int 50016
#define OFFV_OFF  2101376  // int 50016
#define CURV_OFF  2151392  // int 50016
#define BSUM_OFF  2201408  // int 256
#define BBASE_OFF 2201664  // int 256
#define IDXE_OFF  2201920  // int 600000: item ids grouped by edge
#define IDXV_OFF  2801920  // int 600000: item ids grouped by vertex
// Xbf (bf16 X, 6.4M ushort = 12.8 MB) lives in the FRONT of d_out:
//   written by to_bf16, read by edge_reduce, dead before vertex_reduce
//   overwrites d_out with S2.

typedef __attribute__((ext_vector_type(8))) short bf16x8;
typedef __attribute__((ext_vector_type(4))) float f32x4;

__device__ __forceinline__ unsigned short f2bf(float x){
  unsigned u = __float_as_uint(x);
  u += 0x7fffu + ((u >> 16) & 1u);     // round-to-nearest-even
  return (unsigned short)(u >> 16);
}
__device__ __forceinline__ float bf2f(unsigned short h){
  return __uint_as_float((unsigned)h << 16);
}

// ---------------- weight preparation (tiny) ----------------
__global__ __launch_bounds__(128) void prep_weights(
        const float* __restrict__ W1w, const float* __restrict__ W2w,
        const float* __restrict__ W2b, const float* __restrict__ Ww,
        float* __restrict__ ws){
  int b = blockIdx.x, o = threadIdx.x;
  if (b < 384){
    float s;
    if (b < 256){
      float acc = 0.f;
      for (int m = 0; m < 128; ++m) acc += Ww[o*128 + m] * W2w[m*256 + b];
      s = 0.5f * acc;
    } else {
      s = 0.5f * Ww[o*128 + (b - 256)];
    }
    int ks = b >> 5, g = (b >> 3) & 3, j = b & 7;
    int ct = o >> 4, lo = o & 15;
    unsigned short* Bp = (unsigned short*)(ws + BPACK_OFF);
    Bp[((size_t)((ks*8 + ct)*64 + g*16 + lo))*8 + j] = f2bf(s);
  } else if (b < 512){
    int k = b - 384;
    ws[WT1_OFF + k*128 + o] = W1w[o*128 + k];
  } else {
    float acc = 0.f;
    for (int m = 0; m < 128; ++m) acc += Ww[o*128 + m] * W2b[m];
    ws[BA_OFF + o] = 0.5f * acc;
  }
}

// ---------------- histogram ----------------
__global__ __launch_bounds__(256) void count_kernel(
        const int* __restrict__ vertex, const int* __restrict__ edges,
        int* __restrict__ cntE, int* __restrict__ cntV){
  int i = blockIdx.x*256 + threadIdx.x;
  if (i >= NNZV) return;
  atomicAdd(cntE + edges[i], 1);
  atomicAdd(cntV + vertex[i], 1);
}

// ---------------- X -> bf16 copy (into d_out front) ----------------
__global__ __launch_bounds__(256) void to_bf16(
        const float* __restrict__ src, unsigned short* __restrict__ dst, int n8){
  int i = blockIdx.x*256 + threadIdx.x;
  if (i >= n8) return;
  float4 v0 = ((const float4*)src)[(size_t)i*2];
  float4 v1 = ((const float4*)src)[(size_t)i*2 + 1];
  ushort4 h0, h1;
  h0.x=f2bf(v0.x); h0.y=f2bf(v0.y); h0.z=f2bf(v0.z); h0.w=f2bf(v0.w);
  h1.x=f2bf(v1.x); h1.y=f2bf(v1.y); h1.z=f2bf(v1.z); h1.w=f2bf(v1.w);
  ((ushort4*)dst)[(size_t)i*2]     = h0;
  ((ushort4*)dst)[(size_t)i*2 + 1] = h1;
}

// ---------------- hierarchical scan: pass 1 (block sums) ----------------
__global__ __launch_bounds__(256) void scan_partial(
        const int* __restrict__ cntE, const int* __restrict__ cntV,
        int* __restrict__ bsum){
  int bid = blockIdx.x, t = threadIdx.x;
  const int* cnt; int n, li;
  if (bid < NBE){ cnt = cntE; n = NEV; li = bid*256 + t; }
  else          { cnt = cntV; n = NV;  li = (bid - NBE)*256 + t; }
  int c = (li < n) ? cnt[li] : 0;
  __shared__ int s[256];
  s[t] = c; __syncthreads();
  for (int d = 128; d > 0; d >>= 1){
    if (t < d) s[t] += s[t + d];
    __syncthreads();
  }
  if (t == 0) bsum[bid] = s[0];
}

// ---------------- pass 2: scan the block sums (both segments) ----------------
__global__ __launch_bounds__(256) void scan_base(
        const int* __restrict__ bsum, int* __restrict__ bbase,
        int* __restrict__ offE, int* __restrict__ offV){
  __shared__ int s[256];
  int t = threadIdx.x;
  int v = (t < NBE) ? bsum[t] : 0;
  s[t] = v; __syncthreads();
  for (int d = 1; d < 256; d <<= 1){
    int x = (t >= d) ? s[t - d] : 0;
    __syncthreads(); s[t] += x; __syncthreads();
  }
  if (t < NBE) bbase[t] = s[t] - v;
  __syncthreads();
  int v2 = (t < NBV) ? bsum[NBE + t] : 0;
  s[t] = v2; __syncthreads();
  for (int d = 1; d < 256; d <<= 1){
    int x = (t >= d) ? s[t - d] : 0;
    __syncthreads(); s[t] += x; __syncthreads();
  }
  if (t < NBV) bbase[NBE + t] = s[t] - v2;
  if (t == 0){ offE[NEV] = NNZV; offV[NV] = NNZV; }
}

// ---------------- pass 3: per-block exclusive scan + base ----------------
__global__ __launch_bounds__(256) void scan_apply(
        const int* __restrict__ cntE, const int* __restrict__ cntV,
        const int* __restrict__ bbase,
        int* __restrict__ offE, int* __restrict__ curE,
        int* __restrict__ offV, int* __restrict__ curV){
  int bid = blockIdx.x, t = threadIdx.x;
  const int* cnt; int n, li; int* off; int* cur;
  if (bid < NBE){ cnt = cntE; n = NEV; li = bid*256 + t; off = offE; cur = curE; }
  else          { cnt = cntV; n = NV;  li = (bid - NBE)*256 + t; off = offV; cur = curV; }
  int c = (li < n) ? cnt[li] : 0;
  __shared__ int s[256];
  s[t] = c; __syncthreads();
  for (int d = 1; d < 256; d <<= 1){
    int x = (t >= d) ? s[t - d] : 0;
    __syncthreads(); s[t] += x; __syncthreads();
  }
  int excl = s[t] - c + bbase[bid];
  if (li < n){ off[li] = excl; cur[li] = excl; }
}

// ---------------- fill permuted index lists (4B scattered stores) ----------------
__global__ __launch_bounds__(256) void fill_lists(
        const int* __restrict__ vertex, const int* __restrict__ edges,
        int* __restrict__ curE, int* __restrict__ curV,
        int* __restrict__ idxE, int* __restrict__ idxV){
  int i = blockIdx.x*256 + threadIdx.x;
  if (i >= NNZV) return;
  int v = vertex[i], e = edges[i];
  int pE = atomicAdd(curE + e, 1);
  idxE[pE] = i;
  int pV = atomicAdd(curV + v, 1);
  idxV[pV] = i;
}

// ---------------- per-edge reduce: T[e] = sum a*Xbf[v], B[e] = sum a ----------------
__global__ __launch_bounds__(128) void edge_reduce(
        const unsigned short* __restrict__ Xbf, const int* __restrict__ offE,
        const int* __restrict__ idxE,
        const int* __restrict__ vertex, const float* __restrict__ alpha,
        float* __restrict__ T, float* __restrict__ B){
  int e = blockIdx.x, d = threadIdx.x;
  int s0 = offE[e], s1 = offE[e+1];
  __shared__ int   vs[128];
  __shared__ float as[128];
  float acc = 0.f, bacc = 0.f;
  for (int base = s0; base < s1; base += 128){
    int L = min(128, s1 - base);
    __syncthreads();
    if (d < L){
      int i = idxE[base + d];
      vs[d] = vertex[i]; as[d] = alpha[i];
    }
    __syncthreads();
    for (int j = 0; j < L; ++j){
      float a = as[j];
      acc  += a * bf2f(Xbf[(size_t)vs[j]*DIM + d]);
      bacc += a;
    }
  }
  T[(size_t)e*DIM + d] = acc;
  if (d == 0) B[e] = bacc;
}

// ---------------- Xe = T @ Wt1 + B*b1  (writes bf16 XEBF) ----------------
__global__ __launch_bounds__(256) void gemm_xe(const float* __restrict__ W1b,
                                               float* __restrict__ ws){
  __shared__ float Y[32][136];
  const float* T = ws + T_OFF;
  const float* Wt1 = ws + WT1_OFF;
  const float* Bs  = ws + B_OFF;
  unsigned short* Xe = (unsigned short*)(ws + XEBF_OFF);
  int n0 = blockIdx.x * 32;
  int tid = threadIdx.x;
  {
    int lr = tid >> 3, lj = tid & 7;
    int gn = n0 + lr; if (gn >= NEV) gn = NEV - 1;
    const float* src = T + (size_t)gn*DIM + lj*16;
    #pragma unroll
    for (int q = 0; q < 4; ++q)
      *(float4*)(&Y[lr][lj*16 + q*4]) = *(const float4*)(src + q*4);
  }
  __syncthreads();
  int rq = tid >> 5, cq = tid & 31;
  float acc[4][4];
  #pragma unroll
  for (int u=0;u<4;++u){ acc[u][0]=0;acc[u][1]=0;acc[u][2]=0;acc[u][3]=0; }
  const float* Crow = Wt1 + cq*4;
  #pragma unroll 4
  for (int k = 0; k < 128; ++k){
    float4 c = *(const float4*)(Crow + (size_t)k*128);
    #pragma unroll
    for (int u = 0; u < 4; ++u){
      float y = Y[rq*4 + u][k];
      acc[u][0] += y*c.x; acc[u][1] += y*c.y; acc[u][2] += y*c.z; acc[u][3] += y*c.w;
    }
  }
  float4 b1v = *(const float4*)(W1b + cq*4);
  #pragma unroll
  for (int u = 0; u < 4; ++u){
    int e = n0 + rq*4 + u;
    if (e < NEV){
      float Bv = Bs[e];
      ushort4 h;
      h.x = f2bf(acc[u][0] + Bv*b1v.x); h.y = f2bf(acc[u][1] + Bv*b1v.y);
      h.z = f2bf(acc[u][2] + Bv*b1v.z); h.w = f2bf(acc[u][3] + Bv*b1v.w);
      *(ushort4*)(Xe + (size_t)e*DIM + cq*4) = h;
    }
  }
}

// ---------------- per-vertex reduce: S2[v] = sum a*Xe[e] (into out), A[v] = sum a ----------------
__global__ __launch_bounds__(128) void vertex_reduce(
        const unsigned short* __restrict__ Xe, const int* __restrict__ offV,
        const int* __restrict__ idxV,
        const int* __restrict__ edges, const float* __restrict__ alpha,
        float* __restrict__ S2, float* __restrict__ A){
  int v = blockIdx.x, d = threadIdx.x;
  int s0 = offV[v], s1 = offV[v+1];
  __shared__ int   es[128];
  __shared__ float as[128];
  float acc = 0.f, aacc = 0.f;
  for (int base = s0; base < s1; base += 128){
    int L = min(128, s1 - base);
    __syncthreads();
    if (d < L){
      int i = idxV[base + d];
      es[d] = edges[i]; as[d] = alpha[i];
    }
    __syncthreads();
    for (int j = 0; j < L; ++j){
      float a = as[j];
      acc  += a * bf2f(Xe[(size_t)es[j]*DIM + d]);
      aacc += a;
    }
  }
  S2[(size_t)v*DIM + d] = acc;
  if (d == 0) A[v] = aacc;
}

// ---------------- out = [A*X | S2 | X0] @ Ct + A*bA + Wb  via bf16 MFMA ----------------
#define LDS_STRIDE 392   // shorts per row: 384 + 8 pad

__global__ __launch_bounds__(256) void gemm_final_mfma(
        const float* __restrict__ X, const float* __restrict__ X0,
        const float* __restrict__ Wb, const float* __restrict__ ws,
        float* __restrict__ out){
  __shared__ unsigned short At[64 * LDS_STRIDE];
  __shared__ float ArS[64];
  const float* Aa = ws + A_OFF;
  const float* bA = ws + BA_OFF;
  const unsigned short* Bpack = (const unsigned short*)(ws + BPACK_OFF);
  int r0 = blockIdx.x * 64;
  int t = threadIdx.x;
  if (t < 64){
    int gn = r0 + t; if (gn >= NV) gn = NV - 1;
    ArS[t] = Aa[gn];
  }
  __syncthreads();
  #pragma unroll
  for (int seg = 0; seg < 3; ++seg){
    const float* src = (seg == 0) ? X : (seg == 1) ? out : X0;
    #pragma unroll
    for (int i = 0; i < 8; ++i){
      int idx = t + i*256;
      int row = idx >> 5;
      int c4  = idx & 31;
      int gn = r0 + row; if (gn >= NV) gn = NV - 1;
      float4 v = *(const float4*)(src + (size_t)gn*DIM + c4*4);
      if (seg == 0){
        float Ar = ArS[row];
        v.x *= Ar; v.y *= Ar; v.z *= Ar; v.w *= Ar;
      }
      ushort4 h;
      h.x = f2bf(v.x); h.y = f2bf(v.y); h.z = f2bf(v.z); h.w = f2bf(v.w);
      *(ushort4*)(&At[row*LDS_STRIDE + seg*128 + c4*4]) = h;
    }
  }
  __syncthreads();

  int w = t >> 6, l = t & 63;
  int m0 = w * 16;
  int lr = l & 15, lg = l >> 4;
  f32x4 acc[8];
  #pragma unroll
  for (int ct = 0; ct < 8; ++ct) acc[ct] = (f32x4){0.f,0.f,0.f,0.f};

  const unsigned short* arow = &At[(m0 + lr)*LDS_STRIDE + lg*8];
  for (int ks = 0; ks < 12; ++ks){
    bf16x8 af = *(const bf16x8*)(arow + ks*32);
    const bf16x8* bp = (const bf16x8*)(Bpack) + (size_t)ks*8*64 + l;
    #pragma unroll
    for (int ct = 0; ct < 8; ++ct){
      bf16x8 bf = bp[ct*64];
      acc[ct] = __builtin_amdgcn_mfma_f32_16x16x32_bf16(af, bf, acc[ct], 0, 0, 0);
    }
  }

  #pragma unroll
  for (int ct = 0; ct < 8; ++ct){
    int o = ct*16 + lr;
    float ba = bA[o], wb = Wb[o];
    #pragma unroll
    for (int r = 0; r < 4; ++r){
      int lrow = m0 + lg*4 + r;
      int row = r0 + lrow;
      if (row < NV){
        float Av = ArS[lrow];
        out[(size_t)row*DIM + o] = acc[ct][r] + Av*ba + wb;
      }
    }
  }
}

extern "C" void kernel_launch(void* const* d_in, const int* in_sizes, int n_in,
                              void* d_out, int out_size, void* d_ws, size_t ws_size,
                              hipStream_t stream){
  const float* X    = (const float*)d_in[0];
  const int*  vertex= (const int*)  d_in[1];
  const int*  edges = (const int*)  d_in[2];
  const float* X0   = (const float*)d_in[3];
  const float* alpha= (const float*)d_in[4];
  const float* W1w  = (const float*)d_in[5];
  const float* W1b  = (const float*)d_in[6];
  const float* W2w  = (const float*)d_in[7];
  const float* W2b  = (const float*)d_in[8];
  const float* Ww   = (const float*)d_in[9];
  const float* Wb   = (const float*)d_in[10];
  float* out = (float*)d_out;
  float* ws  = (float*)d_ws;

  int* cntE  = (int*)(ws + CNTE_OFF);
  int* offE  = (int*)(ws + OFFE_OFF);
  int* curE  = (int*)(ws + CURE_OFF);
  int* cntV  = (int*)(ws + CNTV_OFF);
  int* offV  = (int*)(ws + OFFV_OFF);
  int* curV  = (int*)(ws + CURV_OFF);
  int* bsum  = (int*)(ws + BSUM_OFF);
  int* bbase = (int*)(ws + BBASE_OFF);
  int* idxE  = (int*)(ws + IDXE_OFF);
  int* idxV  = (int*)(ws + IDXV_OFF);
  unsigned short* Xbf  = (unsigned short*)out;          // front 12.8 MB of d_out
  unsigned short* Xebf = (unsigned short*)(ws + XEBF_OFF);

  hipMemsetAsync(cntE, 0, 10016u * 4, stream);
  hipMemsetAsync(cntV, 0, 50016u * 4, stream);

  prep_weights <<<513, 128, 0, stream>>>(W1w, W2w, W2b, Ww, ws);
  count_kernel <<<(NNZV + 255)/256, 256, 0, stream>>>(vertex, edges, cntE, cntV);
  to_bf16      <<<(NV*DIM/8 + 255)/256, 256, 0, stream>>>(X, Xbf, NV*DIM/8);
  scan_partial <<<NBE + NBV, 256, 0, stream>>>(cntE, cntV, bsum);
  scan_base    <<<1, 256, 0, stream>>>(bsum, bbase, offE, offV);
  scan_apply   <<<NBE + NBV, 256, 0, stream>>>(cntE, cntV, bbase, offE, curE, offV, curV);
  fill_lists   <<<(NNZV + 255)/256, 256, 0, stream>>>(vertex, edges, curE, curV, idxE, idxV);
  edge_reduce  <<<NEV, 128, 0, stream>>>(Xbf, offE, idxE, vertex, alpha,
                                         ws + T_OFF, ws + B_OFF);
  gemm_xe      <<<(NEV + 31)/32, 256, 0, stream>>>(W1b, ws);
  vertex_reduce<<<NV, 128, 0, stream>>>(Xebf, offV, idxV, edges, alpha,
                                        out, ws + A_OFF);
  gemm_final_mfma<<<(NV + 63)/64, 256, 0, stream>>>(X, X0, Wb, ws, out);
}

// Round 7
// 294.803 us; speedup vs baseline: 2.4122x; 1.0093x over previous
//
#include <hip/hip_runtime.h>

#define NV   50000
#define NEV  10000
#define NNZV 600000
#define DIM  128

#define NBE  40     // ceil(NEV/256)  (scan blocks)
#define NBV  196    // ceil(NV/256)

#define NBKE 157    // edge buckets: key>>6  (64 keys each)
#define NBKV 196    // vertex buckets: key>>8 (256 keys each)
#define CHUNK 4096
#define SCAP 7680

// workspace layout (float offsets) — total 3,401,920 floats = 13.6 MB (proven)
#define BPACK_OFF 0        // 24576: bf16 384x128 packed final weights
#define WT1_OFF   24576    // 16384: W1^T fp32 [k][o]
#define BA_OFF    40960    // 256
#define A_OFF     41216    // 50048: per-vertex alpha sum
#define B_OFF     91264    // 10048: per-edge alpha sum
#define T_OFF     101312   // 1280000: f32 T (also int bounce for sort fallback)
#define XEBF_OFF  1381312  // 640000 floats = 1.28M ushort: bf16 Xe
#define CNTE_OFF  2021312  // int 10016
#define OFFE_OFF  2031328  // int 10016
#define CURE_OFF  2041344  // int 10016  (reused as bcurE)
#define CNTV_OFF  2051360  // int 50016
#define OFFV_OFF  2101376  // int 50016
#define CURV_OFF  2151392  // int 50016  (reused as bcurV)
#define BSUM_OFF  2201408  // int 256
#define BBASE_OFF 2201664  // int 256
#define IDXE_OFF  2201920  // int 600000: item ids grouped by edge
#define IDXV_OFF  2801920  // int 600000: item ids grouped by vertex
// Xbf (bf16 X, 12.8 MB) lives in the FRONT of d_out (dead before vertex_reduce).

typedef __attribute__((ext_vector_type(8))) short bf16x8;
typedef __attribute__((ext_vector_type(4))) float f32x4;

__device__ __forceinline__ unsigned short f2bf(float x){
  unsigned u = __float_as_uint(x);
  u += 0x7fffu + ((u >> 16) & 1u);     // round-to-nearest-even
  return (unsigned short)(u >> 16);
}
__device__ __forceinline__ float bf2f(unsigned short h){
  return __uint_as_float((unsigned)h << 16);
}

// ---------------- weight preparation (tiny) ----------------
__global__ __launch_bounds__(128) void prep_weights(
        const float* __restrict__ W1w, const float* __restrict__ W2w,
        const float* __restrict__ W2b, const float* __restrict__ Ww,
        float* __restrict__ ws){
  int b = blockIdx.x, o = threadIdx.x;
  if (b < 384){
    float s;
    if (b < 256){
      float acc = 0.f;
      for (int m = 0; m < 128; ++m) acc += Ww[o*128 + m] * W2w[m*256 + b];
      s = 0.5f * acc;
    } else {
      s = 0.5f * Ww[o*128 + (b - 256)];
    }
    int ks = b >> 5, g = (b >> 3) & 3, j = b & 7;
    int ct = o >> 4, lo = o & 15;
    unsigned short* Bp = (unsigned short*)(ws + BPACK_OFF);
    Bp[((size_t)((ks*8 + ct)*64 + g*16 + lo))*8 + j] = f2bf(s);
  } else if (b < 512){
    int k = b - 384;
    ws[WT1_OFF + k*128 + o] = W1w[o*128 + k];
  } else {
    float acc = 0.f;
    for (int m = 0; m < 128; ++m) acc += Ww[o*128 + m] * W2b[m];
    ws[BA_OFF + o] = 0.5f * acc;
  }
}

// ---------------- histogram ----------------
__global__ __launch_bounds__(256) void count_kernel(
        const int* __restrict__ vertex, const int* __restrict__ edges,
        int* __restrict__ cntE, int* __restrict__ cntV){
  int i = blockIdx.x*256 + threadIdx.x;
  if (i >= NNZV) return;
  atomicAdd(cntE + edges[i], 1);
  atomicAdd(cntV + vertex[i], 1);
}

// ---------------- X -> bf16 copy (into d_out front) ----------------
__global__ __launch_bounds__(256) void to_bf16(
        const float* __restrict__ src, unsigned short* __restrict__ dst, int n8){
  int i = blockIdx.x*256 + threadIdx.x;
  if (i >= n8) return;
  float4 v0 = ((const float4*)src)[(size_t)i*2];
  float4 v1 = ((const float4*)src)[(size_t)i*2 + 1];
  ushort4 h0, h1;
  h0.x=f2bf(v0.x); h0.y=f2bf(v0.y); h0.z=f2bf(v0.z); h0.w=f2bf(v0.w);
  h1.x=f2bf(v1.x); h1.y=f2bf(v1.y); h1.z=f2bf(v1.z); h1.w=f2bf(v1.w);
  ((ushort4*)dst)[(size_t)i*2]     = h0;
  ((ushort4*)dst)[(size_t)i*2 + 1] = h1;
}

// ---------------- hierarchical scan: pass 1 (block sums) ----------------
__global__ __launch_bounds__(256) void scan_partial(
        const int* __restrict__ cntE, const int* __restrict__ cntV,
        int* __restrict__ bsum){
  int bid = blockIdx.x, t = threadIdx.x;
  const int* cnt; int n, li;
  if (bid < NBE){ cnt = cntE; n = NEV; li = bid*256 + t; }
  else          { cnt = cntV; n = NV;  li = (bid - NBE)*256 + t; }
  int c = (li < n) ? cnt[li] : 0;
  __shared__ int s[256];
  s[t] = c; __syncthreads();
  for (int d = 128; d > 0; d >>= 1){
    if (t < d) s[t] += s[t + d];
    __syncthreads();
  }
  if (t == 0) bsum[bid] = s[0];
}

// ---------------- pass 2: scan the block sums (both segments) ----------------
__global__ __launch_bounds__(256) void scan_base(
        const int* __restrict__ bsum, int* __restrict__ bbase,
        int* __restrict__ offE, int* __restrict__ offV){
  __shared__ int s[256];
  int t = threadIdx.x;
  int v = (t < NBE) ? bsum[t] : 0;
  s[t] = v; __syncthreads();
  for (int d = 1; d < 256; d <<= 1){
    int x = (t >= d) ? s[t - d] : 0;
    __syncthreads(); s[t] += x; __syncthreads();
  }
  if (t < NBE) bbase[t] = s[t] - v;
  __syncthreads();
  int v2 = (t < NBV) ? bsum[NBE + t] : 0;
  s[t] = v2; __syncthreads();
  for (int d = 1; d < 256; d <<= 1){
    int x = (t >= d) ? s[t - d] : 0;
    __syncthreads(); s[t] += x; __syncthreads();
  }
  if (t < NBV) bbase[NBE + t] = s[t] - v2;
  if (t == 0){ offE[NEV] = NNZV; offV[NV] = NNZV; }
}

// ---------------- pass 3: per-block exclusive scan + base ----------------
__global__ __launch_bounds__(256) void scan_apply(
        const int* __restrict__ cntE, const int* __restrict__ cntV,
        const int* __restrict__ bbase,
        int* __restrict__ offE, int* __restrict__ offV){
  int bid = blockIdx.x, t = threadIdx.x;
  const int* cnt; int n, li; int* off;
  if (bid < NBE){ cnt = cntE; n = NEV; li = bid*256 + t; off = offE; }
  else          { cnt = cntV; n = NV;  li = (bid - NBE)*256 + t; off = offV; }
  int c = (li < n) ? cnt[li] : 0;
  __shared__ int s[256];
  s[t] = c; __syncthreads();
  for (int d = 1; d < 256; d <<= 1){
    int x = (t >= d) ? s[t - d] : 0;
    __syncthreads(); s[t] += x; __syncthreads();
  }
  int excl = s[t] - c + bbase[bid];
  if (li < n) off[li] = excl;
}

// ---------------- init coarse-bucket cursors from off ----------------
__global__ __launch_bounds__(256) void init_bcur(
        const int* __restrict__ offE, const int* __restrict__ offV,
        int* __restrict__ bcurE, int* __restrict__ bcurV){
  int t = blockIdx.x*256 + threadIdx.x;
  if (t < NBKE) bcurE[t] = offE[t*64];
  if (t < NBKV) bcurV[t] = offV[t*256];
}

// ---------------- pass 1: LDS-aggregated binning into bucket regions ----------------
__global__ __launch_bounds__(256) void fill_binned(
        const int* __restrict__ keys, int* __restrict__ bcur,
        int* __restrict__ idx, int shift, int nbk){
  __shared__ int hist[256], lofs[256], gbase[256], pos[256], ss[256];
  __shared__ int stage[CHUNK];
  int t = threadIdx.x;
  int i0 = blockIdx.x * CHUNK;
  if (t < nbk) hist[t] = 0;
  __syncthreads();
  int kb[16], iv[16];
  #pragma unroll
  for (int r = 0; r < 16; ++r){
    int i = i0 + r*256 + t;
    iv[r] = i;
    int b = -1;
    if (i < NNZV){ b = keys[i] >> shift; atomicAdd(&hist[b], 1); }
    kb[r] = b;
  }
  __syncthreads();
  int c = (t < nbk) ? hist[t] : 0;
  ss[t] = c; __syncthreads();
  for (int d = 1; d < 256; d <<= 1){
    int x = (t >= d) ? ss[t-d] : 0;
    __syncthreads(); ss[t] += x; __syncthreads();
  }
  if (t < nbk){ lofs[t] = ss[t] - c; pos[t] = ss[t] - c; }
  __syncthreads();
  #pragma unroll
  for (int r = 0; r < 16; ++r){
    if (kb[r] >= 0){
      int p = atomicAdd(&pos[kb[r]], 1);
      stage[p] = iv[r];
    }
  }
  __syncthreads();
  if (t < nbk){
    int cnt = hist[t];
    gbase[t] = cnt ? atomicAdd(&bcur[t], cnt) : 0;
  }
  __syncthreads();
  int total = (i0 + CHUNK <= NNZV) ? CHUNK : (NNZV - i0);
  for (int s = t; s < total; s += 256){
    int lo = 0, hi = nbk - 1;                 // largest b with lofs[b] <= s
    while (lo < hi){ int mid = (lo + hi + 1) >> 1; if (lofs[mid] <= s) lo = mid; else hi = mid - 1; }
    idx[gbase[lo] + (s - lofs[lo])] = stage[s];
  }
}

// ---------------- pass 2: in-place counting sort within each bucket ----------------
__global__ __launch_bounds__(256) void sort_bucket(
        const int* __restrict__ keys, const int* __restrict__ off,
        int* __restrict__ idx, int* __restrict__ bounce, int kpb, int nkeys){
  int b = blockIdx.x, t = threadIdx.x;
  int k0 = b * kpb;
  int k1 = min(k0 + kpb, nkeys);
  int r0 = off[k0], r1 = off[k1];
  int m = r1 - r0;
  __shared__ int hist[256], rnk[256], ssc[256];
  __shared__ int srt[SCAP];
  for (int q = t; q < kpb; q += 256) hist[q] = 0;
  __syncthreads();
  int ireg[30], kreg[30];
  #pragma unroll
  for (int r = 0; r < 30; ++r){
    int s = r*256 + t;
    int item = -1, kk = 0;
    if (s < m && m <= SCAP){
      item = idx[r0 + s]; kk = keys[item] - k0;
      atomicAdd(&hist[kk], 1);
    }
    ireg[r] = item; kreg[r] = kk;
  }
  if (m > SCAP){   // never-taken statistically; correct fallback via global bounce
    for (int s = t; s < m; s += 256){
      int item = idx[r0 + s];
      bounce[s] = item;
      atomicAdd(&hist[keys[item] - k0], 1);
    }
  }
  __syncthreads();
  int c = (t < kpb) ? hist[t] : 0;
  ssc[t] = c; __syncthreads();
  for (int d = 1; d < 256; d <<= 1){
    int x = (t >= d) ? ssc[t-d] : 0;
    __syncthreads(); ssc[t] += x; __syncthreads();
  }
  if (t < kpb) rnk[t] = ssc[t] - c;
  __syncthreads();
  if (m <= SCAP){
    #pragma unroll
    for (int r = 0; r < 30; ++r){
      if (ireg[r] >= 0){
        int p = atomicAdd(&rnk[kreg[r]], 1);
        srt[p] = ireg[r];
      }
    }
    __syncthreads();
    for (int s = t; s < m; s += 256) idx[r0 + s] = srt[s];
  } else {
    __syncthreads();
    for (int s = t; s < m; s += 256){
      int item = bounce[s];
      int p = atomicAdd(&rnk[keys[item] - k0], 1);
      idx[r0 + p] = item;
    }
  }
}

// ---------------- per-edge reduce: T[e] = sum a*Xbf[v], B[e] = sum a ----------------
__global__ __launch_bounds__(128) void edge_reduce(
        const unsigned short* __restrict__ Xbf, const int* __restrict__ offE,
        const int* __restrict__ idxE,
        const int* __restrict__ vertex, const float* __restrict__ alpha,
        float* __restrict__ T, float* __restrict__ B){
  int e = blockIdx.x, d = threadIdx.x;
  int s0 = offE[e], s1 = offE[e+1];
  __shared__ int   vs[128];
  __shared__ float as[128];
  float acc = 0.f, bacc = 0.f;
  for (int base = s0; base < s1; base += 128){
    int L = min(128, s1 - base);
    __syncthreads();
    if (d < L){
      int i = idxE[base + d];
      vs[d] = vertex[i]; as[d] = alpha[i];
    }
    __syncthreads();
    for (int j = 0; j < L; ++j){
      float a = as[j];
      acc  += a * bf2f(Xbf[(size_t)vs[j]*DIM + d]);
      bacc += a;
    }
  }
  T[(size_t)e*DIM + d] = acc;
  if (d == 0) B[e] = bacc;
}

// ---------------- Xe = T @ Wt1 + B*b1  (writes bf16 XEBF) ----------------
__global__ __launch_bounds__(256) void gemm_xe(const float* __restrict__ W1b,
                                               float* __restrict__ ws){
  __shared__ float Y[32][136];
  const float* T = ws + T_OFF;
  const float* Wt1 = ws + WT1_OFF;
  const float* Bs  = ws + B_OFF;
  unsigned short* Xe = (unsigned short*)(ws + XEBF_OFF);
  int n0 = blockIdx.x * 32;
  int tid = threadIdx.x;
  {
    int lr = tid >> 3, lj = tid & 7;
    int gn = n0 + lr; if (gn >= NEV) gn = NEV - 1;
    const float* src = T + (size_t)gn*DIM + lj*16;
    #pragma unroll
    for (int q = 0; q < 4; ++q)
      *(float4*)(&Y[lr][lj*16 + q*4]) = *(const float4*)(src + q*4);
  }
  __syncthreads();
  int rq = tid >> 5, cq = tid & 31;
  float acc[4][4];
  #pragma unroll
  for (int u=0;u<4;++u){ acc[u][0]=0;acc[u][1]=0;acc[u][2]=0;acc[u][3]=0; }
  const float* Crow = Wt1 + cq*4;
  #pragma unroll 4
  for (int k = 0; k < 128; ++k){
    float4 c = *(const float4*)(Crow + (size_t)k*128);
    #pragma unroll
    for (int u = 0; u < 4; ++u){
      float y = Y[rq*4 + u][k];
      acc[u][0] += y*c.x; acc[u][1] += y*c.y; acc[u][2] += y*c.z; acc[u][3] += y*c.w;
    }
  }
  float4 b1v = *(const float4*)(W1b + cq*4);
  #pragma unroll
  for (int u = 0; u < 4; ++u){
    int e = n0 + rq*4 + u;
    if (e < NEV){
      float Bv = Bs[e];
      ushort4 h;
      h.x = f2bf(acc[u][0] + Bv*b1v.x); h.y = f2bf(acc[u][1] + Bv*b1v.y);
      h.z = f2bf(acc[u][2] + Bv*b1v.z); h.w = f2bf(acc[u][3] + Bv*b1v.w);
      *(ushort4*)(Xe + (size_t)e*DIM + cq*4) = h;
    }
  }
}

// ---------------- per-vertex reduce: S2[v] = sum a*Xe[e] (into out), A[v] = sum a ----------------
__global__ __launch_bounds__(128) void vertex_reduce(
        const unsigned short* __restrict__ Xe, const int* __restrict__ offV,
        const int* __restrict__ idxV,
        const int* __restrict__ edges, const float* __restrict__ alpha,
        float* __restrict__ S2, float* __restrict__ A){
  int v = blockIdx.x, d = threadIdx.x;
  int s0 = offV[v], s1 = offV[v+1];
  __shared__ int   es[128];
  __shared__ float as[128];
  float acc = 0.f, aacc = 0.f;
  for (int base = s0; base < s1; base += 128){
    int L = min(128, s1 - base);
    __syncthreads();
    if (d < L){
      int i = idxV[base + d];
      es[d] = edges[i]; as[d] = alpha[i];
    }
    __syncthreads();
    for (int j = 0; j < L; ++j){
      float a = as[j];
      acc  += a * bf2f(Xe[(size_t)es[j]*DIM + d]);
      aacc += a;
    }
  }
  S2[(size_t)v*DIM + d] = acc;
  if (d == 0) A[v] = aacc;
}

// ---------------- out = [A*X | S2 | X0] @ Ct + A*bA + Wb  via bf16 MFMA ----------------
#define LDS_STRIDE 392   // shorts per row: 384 + 8 pad

__global__ __launch_bounds__(256) void gemm_final_mfma(
        const float* __restrict__ X, const float* __restrict__ X0,
        const float* __restrict__ Wb, const float* __restrict__ ws,
        float* __restrict__ out){
  __shared__ unsigned short At[64 * LDS_STRIDE];
  __shared__ float ArS[64];
  const float* Aa = ws + A_OFF;
  const float* bA = ws + BA_OFF;
  const unsigned short* Bpack = (const unsigned short*)(ws + BPACK_OFF);
  int r0 = blockIdx.x * 64;
  int t = threadIdx.x;
  if (t < 64){
    int gn = r0 + t; if (gn >= NV) gn = NV - 1;
    ArS[t] = Aa[gn];
  }
  __syncthreads();
  #pragma unroll
  for (int seg = 0; seg < 3; ++seg){
    const float* src = (seg == 0) ? X : (seg == 1) ? out : X0;
    #pragma unroll
    for (int i = 0; i < 8; ++i){
      int idx = t + i*256;
      int row = idx >> 5;
      int c4  = idx & 31;
      int gn = r0 + row; if (gn >= NV) gn = NV - 1;
      float4 v = *(const float4*)(src + (size_t)gn*DIM + c4*4);
      if (seg == 0){
        float Ar = ArS[row];
        v.x *= Ar; v.y *= Ar; v.z *= Ar; v.w *= Ar;
      }
      ushort4 h;
      h.x = f2bf(v.x); h.y = f2bf(v.y); h.z = f2bf(v.z); h.w = f2bf(v.w);
      *(ushort4*)(&At[row*LDS_STRIDE + seg*128 + c4*4]) = h;
    }
  }
  __syncthreads();

  int w = t >> 6, l = t & 63;
  int m0 = w * 16;
  int lr = l & 15, lg = l >> 4;
  f32x4 acc[8];
  #pragma unroll
  for (int ct = 0; ct < 8; ++ct) acc[ct] = (f32x4){0.f,0.f,0.f,0.f};

  const unsigned short* arow = &At[(m0 + lr)*LDS_STRIDE + lg*8];
  for (int ks = 0; ks < 12; ++ks){
    bf16x8 af = *(const bf16x8*)(arow + ks*32);
    const bf16x8* bp = (const bf16x8*)(Bpack) + (size_t)ks*8*64 + l;
    #pragma unroll
    for (int ct = 0; ct < 8; ++ct){
      bf16x8 bf = bp[ct*64];
      acc[ct] = __builtin_amdgcn_mfma_f32_16x16x32_bf16(af, bf, acc[ct], 0, 0, 0);
    }
  }

  #pragma unroll
  for (int ct = 0; ct < 8; ++ct){
    int o = ct*16 + lr;
    float ba = bA[o], wb = Wb[o];
    #pragma unroll
    for (int r = 0; r < 4; ++r){
      int lrow = m0 + lg*4 + r;
      int row = r0 + lrow;
      if (row < NV){
        float Av = ArS[lrow];
        out[(size_t)row*DIM + o] = acc[ct][r] + Av*ba + wb;
      }
    }
  }
}

extern "C" void kernel_launch(void* const* d_in, const int* in_sizes, int n_in,
                              void* d_out, int out_size, void* d_ws, size_t ws_size,
                              hipStream_t stream){
  const float* X    = (const float*)d_in[0];
  const int*  vertex= (const int*)  d_in[1];
  const int*  edges = (const int*)  d_in[2];
  const float* X0   = (const float*)d_in[3];
  const float* alpha= (const float*)d_in[4];
  const float* W1w  = (const float*)d_in[5];
  const float* W1b  = (const float*)d_in[6];
  const float* W2w  = (const float*)d_in[7];
  const float* W2b  = (const float*)d_in[8];
  const float* Ww   = (const float*)d_in[9];
  const float* Wb   = (const float*)d_in[10];
  float* out = (float*)d_out;
  float* ws  = (float*)d_ws;

  int* cntE  = (int*)(ws + CNTE_OFF);
  int* offE  = (int*)(ws + OFFE_OFF);
  int* bcurE = (int*)(ws + CURE_OFF);
  int* cntV  = (int*)(ws + CNTV_OFF);
  int* offV  = (int*)(ws + OFFV_OFF);
  int* bcurV = (int*)(ws + CURV_OFF);
  int* bsum  = (int*)(ws + BSUM_OFF);
  int* bbase = (int*)(ws + BBASE_OFF);
  int* idxE  = (int*)(ws + IDXE_OFF);
  int* idxV  = (int*)(ws + IDXV_OFF);
  int* bounce= (int*)(ws + T_OFF);                      // sort fallback scratch
  unsigned short* Xbf  = (unsigned short*)out;          // front 12.8 MB of d_out
  unsigned short* Xebf = (unsigned short*)(ws + XEBF_OFF);

  hipMemsetAsync(cntE, 0, 10016u * 4, stream);
  hipMemsetAsync(cntV, 0, 50016u * 4, stream);

  prep_weights <<<513, 128, 0, stream>>>(W1w, W2w, W2b, Ww, ws);
  count_kernel <<<(NNZV + 255)/256, 256, 0, stream>>>(vertex, edges, cntE, cntV);
  to_bf16      <<<(NV*DIM/8 + 255)/256, 256, 0, stream>>>(X, Xbf, NV*DIM/8);
  scan_partial <<<NBE + NBV, 256, 0, stream>>>(cntE, cntV, bsum);
  scan_base    <<<1, 256, 0, stream>>>(bsum, bbase, offE, offV);
  scan_apply   <<<NBE + NBV, 256, 0, stream>>>(cntE, cntV, bbase, offE, offV);
  init_bcur    <<<1, 256, 0, stream>>>(offE, offV, bcurE, bcurV);
  fill_binned  <<<(NNZV + CHUNK - 1)/CHUNK, 256, 0, stream>>>(edges,  bcurE, idxE, 6, NBKE);
  fill_binned  <<<(NNZV + CHUNK - 1)/CHUNK, 256, 0, stream>>>(vertex, bcurV, idxV, 8, NBKV);
  sort_bucket  <<<NBKE, 256, 0, stream>>>(edges,  offE, idxE, bounce, 64,  NEV);
  sort_bucket  <<<NBKV, 256, 0, stream>>>(vertex, offV, idxV, bounce, 256, NV);
  edge_reduce  <<<NEV, 128, 0, stream>>>(Xbf, offE, idxE, vertex, alpha,
                                         ws + T_OFF, ws + B_OFF);
  gemm_xe      <<<(NEV + 31)/32, 256, 0, stream>>>(W1b, ws);
  vertex_reduce<<<NV, 128, 0, stream>>>(Xebf, offV, idxV, edges, alpha,
                                        out, ws + A_OFF);
  gemm_final_mfma<<<(NV + 63)/64, 256, 0, stream>>>(X, X0, Wb, ws, out);
}

// Round 8
// 233.482 us; speedup vs baseline: 3.0458x; 1.2626x over previous
//
#include <hip/hip_runtime.h>

#define NV   50000
#define NEV  10000
#define NNZV 600000
#define DIM  128

#define NBKE 157    // edge buckets: key>>6  (64 keys each)
#define NBKV 196    // vertex buckets: key>>8 (256 keys each)
#define CHUNK 4096
#define SCAP 7680

// workspace layout (float offsets) — total 3,401,920 floats = 13.6 MB (proven)
#define BPACK_OFF 0        // 24576: bf16 384x128 packed final weights
#define WT1_OFF   24576    // 16384: W1^T fp32 [k][o]
#define BA_OFF    40960    // 256
#define A_OFF     41216    // 50048: per-vertex alpha sum
#define B_OFF     91264    // 10048: per-edge alpha sum
#define T_OFF     101312   // 1280000: f32 T (also int bounce for sort fallback)
#define XEBF_OFF  1381312  // 640000 floats = 1.28M ushort: bf16 Xe
#define BCNTE_OFF 2021312  // int 256: bucket counts (edges)
#define BOFFE_OFF 2021568  // int 256: bucket offsets (edges)
#define BCNTV_OFF 2021824  // int 256: bucket counts (vertices)
#define BOFFV_OFF 2022080  // int 256: bucket offsets (vertices)
#define OFFE_OFF  2031328  // int 10016: exact-key CSR offsets (edges)
#define CURE_OFF  2041344  // int 10016 (bcurE uses first 157)
#define OFFV_OFF  2101376  // int 50016: exact-key CSR offsets (vertices)
#define CURV_OFF  2151392  // int 50016 (bcurV uses first 196)
#define IDXE_OFF  2201920  // int 600000: item ids grouped by edge
#define IDXV_OFF  2801920  // int 600000: item ids grouped by vertex
// Xbf (bf16 X, 12.8 MB) lives in the FRONT of d_out (dead before vertex_reduce).

typedef __attribute__((ext_vector_type(8))) short bf16x8;
typedef __attribute__((ext_vector_type(4))) float f32x4;

__device__ __forceinline__ unsigned short f2bf(float x){
  unsigned u = __float_as_uint(x);
  u += 0x7fffu + ((u >> 16) & 1u);     // round-to-nearest-even
  return (unsigned short)(u >> 16);
}
__device__ __forceinline__ float bf2f(unsigned short h){
  return __uint_as_float((unsigned)h << 16);
}

// ---------------- weight preparation (tiny) ----------------
__global__ __launch_bounds__(128) void prep_weights(
        const float* __restrict__ W1w, const float* __restrict__ W2w,
        const float* __restrict__ W2b, const float* __restrict__ Ww,
        float* __restrict__ ws){
  int b = blockIdx.x, o = threadIdx.x;
  if (b < 384){
    float s;
    if (b < 256){
      float acc = 0.f;
      for (int m = 0; m < 128; ++m) acc += Ww[o*128 + m] * W2w[m*256 + b];
      s = 0.5f * acc;
    } else {
      s = 0.5f * Ww[o*128 + (b - 256)];
    }
    int ks = b >> 5, g = (b >> 3) & 3, j = b & 7;
    int ct = o >> 4, lo = o & 15;
    unsigned short* Bp = (unsigned short*)(ws + BPACK_OFF);
    Bp[((size_t)((ks*8 + ct)*64 + g*16 + lo))*8 + j] = f2bf(s);
  } else if (b < 512){
    int k = b - 384;
    ws[WT1_OFF + k*128 + o] = W1w[o*128 + k];
  } else {
    float acc = 0.f;
    for (int m = 0; m < 128; ++m) acc += Ww[o*128 + m] * W2b[m];
    ws[BA_OFF + o] = 0.5f * acc;
  }
}

// ---------------- bucket-granularity histogram (LDS-aggregated) ----------------
__global__ __launch_bounds__(256) void count_bucket(
        const int* __restrict__ vertex, const int* __restrict__ edges,
        int* __restrict__ bcntE, int* __restrict__ bcntV){
  __shared__ int hE[256], hV[256];
  int t = threadIdx.x;
  hE[t] = 0; hV[t] = 0;
  __syncthreads();
  int i0 = blockIdx.x * 2048;
  #pragma unroll
  for (int r = 0; r < 8; ++r){
    int i = i0 + r*256 + t;
    if (i < NNZV){
      atomicAdd(&hE[edges[i]  >> 6], 1);
      atomicAdd(&hV[vertex[i] >> 8], 1);
    }
  }
  __syncthreads();
  if (hE[t]) atomicAdd(bcntE + t, hE[t]);
  if (hV[t]) atomicAdd(bcntV + t, hV[t]);
}

// ---------------- X -> bf16 copy (into d_out front) ----------------
__global__ __launch_bounds__(256) void to_bf16(
        const float* __restrict__ src, unsigned short* __restrict__ dst, int n8){
  int i = blockIdx.x*256 + threadIdx.x;
  if (i >= n8) return;
  float4 v0 = ((const float4*)src)[(size_t)i*2];
  float4 v1 = ((const float4*)src)[(size_t)i*2 + 1];
  ushort4 h0, h1;
  h0.x=f2bf(v0.x); h0.y=f2bf(v0.y); h0.z=f2bf(v0.z); h0.w=f2bf(v0.w);
  h1.x=f2bf(v1.x); h1.y=f2bf(v1.y); h1.z=f2bf(v1.z); h1.w=f2bf(v1.w);
  ((ushort4*)dst)[(size_t)i*2]     = h0;
  ((ushort4*)dst)[(size_t)i*2 + 1] = h1;
}

// ---------------- tiny: scan bucket counts, init cursors, set tail offs ----------------
__global__ __launch_bounds__(256) void scan_buckets(
        const int* __restrict__ bcntE, const int* __restrict__ bcntV,
        int* __restrict__ bOffE, int* __restrict__ bOffV,
        int* __restrict__ bcurE, int* __restrict__ bcurV,
        int* __restrict__ offE, int* __restrict__ offV){
  __shared__ int s[256];
  int t = threadIdx.x;
  int c = (t < NBKE) ? bcntE[t] : 0;
  s[t] = c; __syncthreads();
  for (int d = 1; d < 256; d <<= 1){
    int x = (t >= d) ? s[t-d] : 0;
    __syncthreads(); s[t] += x; __syncthreads();
  }
  if (t < NBKE){ bOffE[t] = s[t] - c; bcurE[t] = s[t] - c; }
  if (t == 0){ bOffE[NBKE] = NNZV; offE[NEV] = NNZV; }
  __syncthreads();
  int c2 = (t < NBKV) ? bcntV[t] : 0;
  s[t] = c2; __syncthreads();
  for (int d = 1; d < 256; d <<= 1){
    int x = (t >= d) ? s[t-d] : 0;
    __syncthreads(); s[t] += x; __syncthreads();
  }
  if (t < NBKV){ bOffV[t] = s[t] - c2; bcurV[t] = s[t] - c2; }
  if (t == 0){ bOffV[NBKV] = NNZV; offV[NV] = NNZV; }
}

// ---------------- pass 1: LDS-aggregated binning into bucket regions ----------------
__global__ __launch_bounds__(256) void fill_binned(
        const int* __restrict__ keys, int* __restrict__ bcur,
        int* __restrict__ idx, int shift, int nbk){
  __shared__ int hist[256], lofs[256], gbase[256], pos[256], ss[256];
  __shared__ int stage[CHUNK];
  int t = threadIdx.x;
  int i0 = blockIdx.x * CHUNK;
  if (t < nbk) hist[t] = 0;
  __syncthreads();
  int kb[16], iv[16];
  #pragma unroll
  for (int r = 0; r < 16; ++r){
    int i = i0 + r*256 + t;
    iv[r] = i;
    int b = -1;
    if (i < NNZV){ b = keys[i] >> shift; atomicAdd(&hist[b], 1); }
    kb[r] = b;
  }
  __syncthreads();
  int c = (t < nbk) ? hist[t] : 0;
  ss[t] = c; __syncthreads();
  for (int d = 1; d < 256; d <<= 1){
    int x = (t >= d) ? ss[t-d] : 0;
    __syncthreads(); ss[t] += x; __syncthreads();
  }
  if (t < nbk){ lofs[t] = ss[t] - c; pos[t] = ss[t] - c; }
  __syncthreads();
  #pragma unroll
  for (int r = 0; r < 16; ++r){
    if (kb[r] >= 0){
      int p = atomicAdd(&pos[kb[r]], 1);
      stage[p] = iv[r];
    }
  }
  __syncthreads();
  if (t < nbk){
    int cnt = hist[t];
    gbase[t] = cnt ? atomicAdd(&bcur[t], cnt) : 0;
  }
  __syncthreads();
  int total = (i0 + CHUNK <= NNZV) ? CHUNK : (NNZV - i0);
  for (int s = t; s < total; s += 256){
    int lo = 0, hi = nbk - 1;                 // largest b with lofs[b] <= s
    while (lo < hi){ int mid = (lo + hi + 1) >> 1; if (lofs[mid] <= s) lo = mid; else hi = mid - 1; }
    idx[gbase[lo] + (s - lofs[lo])] = stage[s];
  }
}

// ---------------- pass 2: in-bucket counting sort + write exact-key off ----------------
__global__ __launch_bounds__(256) void sort_bucket(
        const int* __restrict__ keys, const int* __restrict__ bOff,
        int* __restrict__ idx, int* __restrict__ off,
        int* __restrict__ bounce, int kpb, int nkeys){
  int b = blockIdx.x, t = threadIdx.x;
  int k0 = b * kpb;
  int r0 = bOff[b], r1 = bOff[b+1];
  int m = r1 - r0;
  __shared__ int hist[256], rnk[256], ssc[256];
  __shared__ int srt[SCAP];
  for (int q = t; q < kpb; q += 256) hist[q] = 0;
  __syncthreads();
  int ireg[30], kreg[30];
  #pragma unroll
  for (int r = 0; r < 30; ++r){
    int s = r*256 + t;
    int item = -1, kk = 0;
    if (s < m && m <= SCAP){
      item = idx[r0 + s]; kk = keys[item] - k0;
      atomicAdd(&hist[kk], 1);
    }
    ireg[r] = item; kreg[r] = kk;
  }
  if (m > SCAP){   // statistically never taken; correct fallback via global bounce
    for (int s = t; s < m; s += 256){
      int item = idx[r0 + s];
      bounce[s] = item;
      atomicAdd(&hist[keys[item] - k0], 1);
    }
  }
  __syncthreads();
  int c = (t < kpb) ? hist[t] : 0;
  ssc[t] = c; __syncthreads();
  for (int d = 1; d < 256; d <<= 1){
    int x = (t >= d) ? ssc[t-d] : 0;
    __syncthreads(); ssc[t] += x; __syncthreads();
  }
  if (t < kpb){
    rnk[t] = ssc[t] - c;
    int k = k0 + t;
    if (k < nkeys) off[k] = r0 + ssc[t] - c;   // exact-key CSR offset
  }
  __syncthreads();
  if (m <= SCAP){
    #pragma unroll
    for (int r = 0; r < 30; ++r){
      if (ireg[r] >= 0){
        int p = atomicAdd(&rnk[kreg[r]], 1);
        srt[p] = ireg[r];
      }
    }
    __syncthreads();
    for (int s = t; s < m; s += 256) idx[r0 + s] = srt[s];
  } else {
    __syncthreads();
    for (int s = t; s < m; s += 256){
      int item = bounce[s];
      int p = atomicAdd(&rnk[keys[item] - k0], 1);
      idx[r0 + p] = item;
    }
  }
}

// ---------------- per-edge reduce: T[e] = sum a*Xbf[v], B[e] = sum a ----------------
__global__ __launch_bounds__(128) void edge_reduce(
        const unsigned short* __restrict__ Xbf, const int* __restrict__ offE,
        const int* __restrict__ idxE,
        const int* __restrict__ vertex, const float* __restrict__ alpha,
        float* __restrict__ T, float* __restrict__ B){
  int e = blockIdx.x, d = threadIdx.x;
  int s0 = offE[e], s1 = offE[e+1];
  __shared__ int   vs[128];
  __shared__ float as[128];
  float acc = 0.f, bacc = 0.f;
  for (int base = s0; base < s1; base += 128){
    int L = min(128, s1 - base);
    __syncthreads();
    if (d < L){
      int i = idxE[base + d];
      vs[d] = vertex[i]; as[d] = alpha[i];
    }
    __syncthreads();
    for (int j = 0; j < L; ++j){
      float a = as[j];
      acc  += a * bf2f(Xbf[(size_t)vs[j]*DIM + d]);
      bacc += a;
    }
  }
  T[(size_t)e*DIM + d] = acc;
  if (d == 0) B[e] = bacc;
}

// ---------------- Xe = T @ Wt1 + B*b1  (writes bf16 XEBF) ----------------
__global__ __launch_bounds__(256) void gemm_xe(const float* __restrict__ W1b,
                                               float* __restrict__ ws){
  __shared__ float Y[32][136];
  const float* T = ws + T_OFF;
  const float* Wt1 = ws + WT1_OFF;
  const float* Bs  = ws + B_OFF;
  unsigned short* Xe = (unsigned short*)(ws + XEBF_OFF);
  int n0 = blockIdx.x * 32;
  int tid = threadIdx.x;
  {
    int lr = tid >> 3, lj = tid & 7;
    int gn = n0 + lr; if (gn >= NEV) gn = NEV - 1;
    const float* src = T + (size_t)gn*DIM + lj*16;
    #pragma unroll
    for (int q = 0; q < 4; ++q)
      *(float4*)(&Y[lr][lj*16 + q*4]) = *(const float4*)(src + q*4);
  }
  __syncthreads();
  int rq = tid >> 5, cq = tid & 31;
  float acc[4][4];
  #pragma unroll
  for (int u=0;u<4;++u){ acc[u][0]=0;acc[u][1]=0;acc[u][2]=0;acc[u][3]=0; }
  const float* Crow = Wt1 + cq*4;
  #pragma unroll 4
  for (int k = 0; k < 128; ++k){
    float4 c = *(const float4*)(Crow + (size_t)k*128);
    #pragma unroll
    for (int u = 0; u < 4; ++u){
      float y = Y[rq*4 + u][k];
      acc[u][0] += y*c.x; acc[u][1] += y*c.y; acc[u][2] += y*c.z; acc[u][3] += y*c.w;
    }
  }
  float4 b1v = *(const float4*)(W1b + cq*4);
  #pragma unroll
  for (int u = 0; u < 4; ++u){
    int e = n0 + rq*4 + u;
    if (e < NEV){
      float Bv = Bs[e];
      ushort4 h;
      h.x = f2bf(acc[u][0] + Bv*b1v.x); h.y = f2bf(acc[u][1] + Bv*b1v.y);
      h.z = f2bf(acc[u][2] + Bv*b1v.z); h.w = f2bf(acc[u][3] + Bv*b1v.w);
      *(ushort4*)(Xe + (size_t)e*DIM + cq*4) = h;
    }
  }
}

// ---------------- per-vertex reduce: S2[v] = sum a*Xe[e] (into out), A[v] = sum a ----------------
__global__ __launch_bounds__(128) void vertex_reduce(
        const unsigned short* __restrict__ Xe, const int* __restrict__ offV,
        const int* __restrict__ idxV,
        const int* __restrict__ edges, const float* __restrict__ alpha,
        float* __restrict__ S2, float* __restrict__ A){
  int v = blockIdx.x, d = threadIdx.x;
  int s0 = offV[v], s1 = offV[v+1];
  __shared__ int   es[128];
  __shared__ float as[128];
  float acc = 0.f, aacc = 0.f;
  for (int base = s0; base < s1; base += 128){
    int L = min(128, s1 - base);
    __syncthreads();
    if (d < L){
      int i = idxV[base + d];
      es[d] = edges[i]; as[d] = alpha[i];
    }
    __syncthreads();
    for (int j = 0; j < L; ++j){
      float a = as[j];
      acc  += a * bf2f(Xe[(size_t)es[j]*DIM + d]);
      aacc += a;
    }
  }
  S2[(size_t)v*DIM + d] = acc;
  if (d == 0) A[v] = aacc;
}

// ---------------- out = [A*X | S2 | X0] @ Ct + A*bA + Wb  via bf16 MFMA ----------------
#define LDS_STRIDE 392   // shorts per row: 384 + 8 pad

__global__ __launch_bounds__(256) void gemm_final_mfma(
        const float* __restrict__ X, const float* __restrict__ X0,
        const float* __restrict__ Wb, const float* __restrict__ ws,
        float* __restrict__ out){
  __shared__ unsigned short At[64 * LDS_STRIDE];
  __shared__ float ArS[64];
  const float* Aa = ws + A_OFF;
  const float* bA = ws + BA_OFF;
  const unsigned short* Bpack = (const unsigned short*)(ws + BPACK_OFF);
  int r0 = blockIdx.x * 64;
  int t = threadIdx.x;
  if (t < 64){
    int gn = r0 + t; if (gn >= NV) gn = NV - 1;
    ArS[t] = Aa[gn];
  }
  __syncthreads();
  #pragma unroll
  for (int seg = 0; seg < 3; ++seg){
    const float* src = (seg == 0) ? X : (seg == 1) ? out : X0;
    #pragma unroll
    for (int i = 0; i < 8; ++i){
      int idx = t + i*256;
      int row = idx >> 5;
      int c4  = idx & 31;
      int gn = r0 + row; if (gn >= NV) gn = NV - 1;
      float4 v = *(const float4*)(src + (size_t)gn*DIM + c4*4);
      if (seg == 0){
        float Ar = ArS[row];
        v.x *= Ar; v.y *= Ar; v.z *= Ar; v.w *= Ar;
      }
      ushort4 h;
      h.x = f2bf(v.x); h.y = f2bf(v.y); h.z = f2bf(v.z); h.w = f2bf(v.w);
      *(ushort4*)(&At[row*LDS_STRIDE + seg*128 + c4*4]) = h;
    }
  }
  __syncthreads();

  int w = t >> 6, l = t & 63;
  int m0 = w * 16;
  int lr = l & 15, lg = l >> 4;
  f32x4 acc[8];
  #pragma unroll
  for (int ct = 0; ct < 8; ++ct) acc[ct] = (f32x4){0.f,0.f,0.f,0.f};

  const unsigned short* arow = &At[(m0 + lr)*LDS_STRIDE + lg*8];
  for (int ks = 0; ks < 12; ++ks){
    bf16x8 af = *(const bf16x8*)(arow + ks*32);
    const bf16x8* bp = (const bf16x8*)(Bpack) + (size_t)ks*8*64 + l;
    #pragma unroll
    for (int ct = 0; ct < 8; ++ct){
      bf16x8 bf = bp[ct*64];
      acc[ct] = __builtin_amdgcn_mfma_f32_16x16x32_bf16(af, bf, acc[ct], 0, 0, 0);
    }
  }

  #pragma unroll
  for (int ct = 0; ct < 8; ++ct){
    int o = ct*16 + lr;
    float ba = bA[o], wb = Wb[o];
    #pragma unroll
    for (int r = 0; r < 4; ++r){
      int lrow = m0 + lg*4 + r;
      int row = r0 + lrow;
      if (row < NV){
        float Av = ArS[lrow];
        out[(size_t)row*DIM + o] = acc[ct][r] + Av*ba + wb;
      }
    }
  }
}

extern "C" void kernel_launch(void* const* d_in, const int* in_sizes, int n_in,
                              void* d_out, int out_size, void* d_ws, size_t ws_size,
                              hipStream_t stream){
  const float* X    = (const float*)d_in[0];
  const int*  vertex= (const int*)  d_in[1];
  const int*  edges = (const int*)  d_in[2];
  const float* X0   = (const float*)d_in[3];
  const float* alpha= (const float*)d_in[4];
  const float* W1w  = (const float*)d_in[5];
  const float* W1b  = (const float*)d_in[6];
  const float* W2w  = (const float*)d_in[7];
  const float* W2b  = (const float*)d_in[8];
  const float* Ww   = (const float*)d_in[9];
  const float* Wb   = (const float*)d_in[10];
  float* out = (float*)d_out;
  float* ws  = (float*)d_ws;

  int* bcntE = (int*)(ws + BCNTE_OFF);
  int* bOffE = (int*)(ws + BOFFE_OFF);
  int* bcntV = (int*)(ws + BCNTV_OFF);
  int* bOffV = (int*)(ws + BOFFV_OFF);
  int* offE  = (int*)(ws + OFFE_OFF);
  int* bcurE = (int*)(ws + CURE_OFF);
  int* offV  = (int*)(ws + OFFV_OFF);
  int* bcurV = (int*)(ws + CURV_OFF);
  int* idxE  = (int*)(ws + IDXE_OFF);
  int* idxV  = (int*)(ws + IDXV_OFF);
  int* bounce= (int*)(ws + T_OFF);                      // sort fallback scratch
  unsigned short* Xbf  = (unsigned short*)out;          // front 12.8 MB of d_out
  unsigned short* Xebf = (unsigned short*)(ws + XEBF_OFF);

  hipMemsetAsync(ws + BCNTE_OFF, 0, 1024u * 4, stream); // zero bcntE..bOffV block

  prep_weights <<<513, 128, 0, stream>>>(W1w, W2w, W2b, Ww, ws);
  count_bucket <<<(NNZV + 2047)/2048, 256, 0, stream>>>(vertex, edges, bcntE, bcntV);
  to_bf16      <<<(NV*DIM/8 + 255)/256, 256, 0, stream>>>(X, Xbf, NV*DIM/8);
  scan_buckets <<<1, 256, 0, stream>>>(bcntE, bcntV, bOffE, bOffV, bcurE, bcurV, offE, offV);
  fill_binned  <<<(NNZV + CHUNK - 1)/CHUNK, 256, 0, stream>>>(edges,  bcurE, idxE, 6, NBKE);
  fill_binned  <<<(NNZV + CHUNK - 1)/CHUNK, 256, 0, stream>>>(vertex, bcurV, idxV, 8, NBKV);
  sort_bucket  <<<NBKE, 256, 0, stream>>>(edges,  bOffE, idxE, offE, bounce, 64,  NEV);
  sort_bucket  <<<NBKV, 256, 0, stream>>>(vertex, bOffV, idxV, offV, bounce, 256, NV);
  edge_reduce  <<<NEV, 128, 0, stream>>>(Xbf, offE, idxE, vertex, alpha,
                                         ws + T_OFF, ws + B_OFF);
  gemm_xe      <<<(NEV + 31)/32, 256, 0, stream>>>(W1b, ws);
  vertex_reduce<<<NV, 128, 0, stream>>>(Xebf, offV, idxV, edges, alpha,
                                        out, ws + A_OFF);
  gemm_final_mfma<<<(NV + 63)/64, 256, 0, stream>>>(X, X0, Wb, ws, out);
}

// Round 9
// 205.268 us; speedup vs baseline: 3.4644x; 1.1375x over previous
//
#include <hip/hip_runtime.h>

#define NV   50000
#define NEV  10000
#define NNZV 600000
#define DIM  128

#define NBKE 157    // edge buckets: e>>6  (64 keys each)
#define NBKV 196    // vertex buckets: v>>8 (256 keys each)
#define CHUNK 4096
#define SCAP 7680

// workspace layout (float offsets) — total 3,401,920 floats = 13.6 MB (proven)
#define BPACK_OFF 0        // 24576: bf16 384x128 packed final weights
#define WT1_OFF   24576    // 16384: W1^T fp32 [k][o]
#define BA_OFF    40960    // 256
#define A_OFF     41216    // 50048: per-vertex alpha sum
#define B_OFF     91264    // 10048: per-edge alpha sum
#define T_OFF     101312   // 1280000: f32 T (also int2 bounce for sort fallback)
#define XEBF_OFF  1381312  // 640000 floats: bf16 Xe (1.28M ushort)
#define BCNTE_OFF 2021312  // int 256: bucket counts (edges)
#define BOFFE_OFF 2021568  // int 256: bucket offsets (edges)
#define BCNTV_OFF 2021824  // int 256: bucket counts (vertices)
#define BOFFV_OFF 2022080  // int 256: bucket offsets (vertices)
#define OFFE_OFF  2031328  // int 10016: exact-key CSR offsets (edges)
#define CURE_OFF  2041344  // int 10016 (bcurE uses first 157)
#define OFFV_OFF  2101376  // int 50016: exact-key CSR offsets (vertices)
#define CURV_OFF  2151392  // int 50016 (bcurV uses first 196)
#define PV_OFF    2201920  // int2 600000: (v<<14|e, alpha) grouped by vertex — 1.2M ints
// PE pairs (int2 600000, 4.8 MB) live in d_out[3.2M floats ..]: written by
// fill_binned/sort, read by edge_reduce, dead before vertex_reduce writes S2.
// Xbf (bf16 X, 12.8 MB) lives in d_out front (dead before vertex_reduce).
#define PE_OUT_FLOAT_OFF 3200000

typedef __attribute__((ext_vector_type(8))) short bf16x8;
typedef __attribute__((ext_vector_type(4))) float f32x4;

__device__ __forceinline__ unsigned short f2bf(float x){
  unsigned u = __float_as_uint(x);
  u += 0x7fffu + ((u >> 16) & 1u);     // round-to-nearest-even
  return (unsigned short)(u >> 16);
}
__device__ __forceinline__ float bf2f(unsigned short h){
  return __uint_as_float((unsigned)h << 16);
}

// ---------------- weight preparation (tiny) ----------------
__global__ __launch_bounds__(128) void prep_weights(
        const float* __restrict__ W1w, const float* __restrict__ W2w,
        const float* __restrict__ W2b, const float* __restrict__ Ww,
        float* __restrict__ ws){
  int b = blockIdx.x, o = threadIdx.x;
  if (b < 384){
    float s;
    if (b < 256){
      float acc = 0.f;
      for (int m = 0; m < 128; ++m) acc += Ww[o*128 + m] * W2w[m*256 + b];
      s = 0.5f * acc;
    } else {
      s = 0.5f * Ww[o*128 + (b - 256)];
    }
    int ks = b >> 5, g = (b >> 3) & 3, j = b & 7;
    int ct = o >> 4, lo = o & 15;
    unsigned short* Bp = (unsigned short*)(ws + BPACK_OFF);
    Bp[((size_t)((ks*8 + ct)*64 + g*16 + lo))*8 + j] = f2bf(s);
  } else if (b < 512){
    int k = b - 384;
    ws[WT1_OFF + k*128 + o] = W1w[o*128 + k];
  } else {
    float acc = 0.f;
    for (int m = 0; m < 128; ++m) acc += Ww[o*128 + m] * W2b[m];
    ws[BA_OFF + o] = 0.5f * acc;
  }
}

// ---------------- bucket-granularity histogram (LDS-aggregated) ----------------
__global__ __launch_bounds__(256) void count_bucket(
        const int* __restrict__ vertex, const int* __restrict__ edges,
        int* __restrict__ bcntE, int* __restrict__ bcntV){
  __shared__ int hE[256], hV[256];
  int t = threadIdx.x;
  hE[t] = 0; hV[t] = 0;
  __syncthreads();
  int i0 = blockIdx.x * 2048;
  #pragma unroll
  for (int r = 0; r < 8; ++r){
    int i = i0 + r*256 + t;
    if (i < NNZV){
      atomicAdd(&hE[edges[i]  >> 6], 1);
      atomicAdd(&hV[vertex[i] >> 8], 1);
    }
  }
  __syncthreads();
  if (hE[t]) atomicAdd(bcntE + t, hE[t]);
  if (hV[t]) atomicAdd(bcntV + t, hV[t]);
}

// ---------------- X -> bf16 copy (into d_out front) ----------------
__global__ __launch_bounds__(256) void to_bf16(
        const float* __restrict__ src, unsigned short* __restrict__ dst, int n8){
  int i = blockIdx.x*256 + threadIdx.x;
  if (i >= n8) return;
  float4 v0 = ((const float4*)src)[(size_t)i*2];
  float4 v1 = ((const float4*)src)[(size_t)i*2 + 1];
  ushort4 h0, h1;
  h0.x=f2bf(v0.x); h0.y=f2bf(v0.y); h0.z=f2bf(v0.z); h0.w=f2bf(v0.w);
  h1.x=f2bf(v1.x); h1.y=f2bf(v1.y); h1.z=f2bf(v1.z); h1.w=f2bf(v1.w);
  ((ushort4*)dst)[(size_t)i*2]     = h0;
  ((ushort4*)dst)[(size_t)i*2 + 1] = h1;
}

// ---------------- tiny: scan bucket counts, init cursors, set tail offs ----------------
__global__ __launch_bounds__(256) void scan_buckets(
        const int* __restrict__ bcntE, const int* __restrict__ bcntV,
        int* __restrict__ bOffE, int* __restrict__ bOffV,
        int* __restrict__ bcurE, int* __restrict__ bcurV,
        int* __restrict__ offE, int* __restrict__ offV){
  __shared__ int s[256];
  int t = threadIdx.x;
  int c = (t < NBKE) ? bcntE[t] : 0;
  s[t] = c; __syncthreads();
  for (int d = 1; d < 256; d <<= 1){
    int x = (t >= d) ? s[t-d] : 0;
    __syncthreads(); s[t] += x; __syncthreads();
  }
  if (t < NBKE){ bOffE[t] = s[t] - c; bcurE[t] = s[t] - c; }
  if (t == 0){ bOffE[NBKE] = NNZV; offE[NEV] = NNZV; }
  __syncthreads();
  int c2 = (t < NBKV) ? bcntV[t] : 0;
  s[t] = c2; __syncthreads();
  for (int d = 1; d < 256; d <<= 1){
    int x = (t >= d) ? s[t-d] : 0;
    __syncthreads(); s[t] += x; __syncthreads();
  }
  if (t < NBKV){ bOffV[t] = s[t] - c2; bcurV[t] = s[t] - c2; }
  if (t == 0){ bOffV[NBKV] = NNZV; offV[NV] = NNZV; }
}

// ---------------- pass 1: LDS-aggregated binning of (packed,alpha) pairs ----------------
// isE: packed = (e<<16)|v, else (v<<14)|e.  bucket = packed>>22 in both cases.
__global__ __launch_bounds__(256) void fill_binned(
        const int* __restrict__ vertex, const int* __restrict__ edges,
        const float* __restrict__ alpha,
        int* __restrict__ bcur, int2* __restrict__ pairs,
        int isE, int nbk){
  __shared__ int hist[256], lofs[256], gbase[256], pos[256], ss[256];
  __shared__ int2 stage[CHUNK];
  int t = threadIdx.x;
  int i0 = blockIdx.x * CHUNK;
  if (t < nbk) hist[t] = 0;
  __syncthreads();
  int pk[16], pa[16], kb[16];
  #pragma unroll
  for (int r = 0; r < 16; ++r){
    int i = i0 + r*256 + t;
    int b = -1, packed = 0, ab = 0;
    if (i < NNZV){
      int v = vertex[i], e = edges[i];
      ab = __float_as_int(alpha[i]);
      packed = isE ? ((e << 16) | v) : ((v << 14) | e);
      b = packed >> 22;
      atomicAdd(&hist[b], 1);
    }
    pk[r] = packed; pa[r] = ab; kb[r] = b;
  }
  __syncthreads();
  int c = (t < nbk) ? hist[t] : 0;
  ss[t] = c; __syncthreads();
  for (int d = 1; d < 256; d <<= 1){
    int x = (t >= d) ? ss[t-d] : 0;
    __syncthreads(); ss[t] += x; __syncthreads();
  }
  if (t < nbk){ lofs[t] = ss[t] - c; pos[t] = ss[t] - c; }
  __syncthreads();
  #pragma unroll
  for (int r = 0; r < 16; ++r){
    if (kb[r] >= 0){
      int p = atomicAdd(&pos[kb[r]], 1);
      stage[p] = make_int2(pk[r], pa[r]);
    }
  }
  __syncthreads();
  if (t < nbk){
    int cnt = hist[t];
    gbase[t] = cnt ? atomicAdd(&bcur[t], cnt) : 0;
  }
  __syncthreads();
  int total = (i0 + CHUNK <= NNZV) ? CHUNK : (NNZV - i0);
  for (int s = t; s < total; s += 256){
    int lo = 0, hi = nbk - 1;                 // largest b with lofs[b] <= s
    while (lo < hi){ int mid = (lo + hi + 1) >> 1; if (lofs[mid] <= s) lo = mid; else hi = mid - 1; }
    pairs[gbase[lo] + (s - lofs[lo])] = stage[s];
  }
}

// ---------------- pass 2: in-bucket counting sort of pairs + exact-key off ----------------
__global__ __launch_bounds__(256) void sort_bucket(
        int2* __restrict__ pairs, const int* __restrict__ bOff,
        int* __restrict__ off, int2* __restrict__ bounce,
        int kpb, int shift, int nkeys){
  int b = blockIdx.x, t = threadIdx.x;
  int k0 = b * kpb;
  int r0 = bOff[b], r1 = bOff[b+1];
  int m = r1 - r0;
  __shared__ int hist[256], rnk[256], ssc[256];
  __shared__ int2 srt[SCAP];
  for (int q = t; q < kpb; q += 256) hist[q] = 0;
  __syncthreads();
  int px[30], py[30];
  #pragma unroll
  for (int r = 0; r < 30; ++r){
    int s = r*256 + t;
    int x = -1, y = 0;
    if (s < m && m <= SCAP){
      int2 p = pairs[r0 + s];
      x = p.x; y = p.y;
      atomicAdd(&hist[(x >> shift) - k0], 1);
    }
    px[r] = x; py[r] = y;
  }
  if (m > SCAP){   // statistically never taken; correct fallback via global bounce
    for (int s = t; s < m; s += 256){
      int2 p = pairs[r0 + s];
      bounce[s] = p;
      atomicAdd(&hist[(p.x >> shift) - k0], 1);
    }
  }
  __syncthreads();
  int c = (t < kpb) ? hist[t] : 0;
  ssc[t] = c; __syncthreads();
  for (int d = 1; d < 256; d <<= 1){
    int x = (t >= d) ? ssc[t-d] : 0;
    __syncthreads(); ssc[t] += x; __syncthreads();
  }
  if (t < kpb){
    rnk[t] = ssc[t] - c;
    int k = k0 + t;
    if (k < nkeys) off[k] = r0 + ssc[t] - c;   // exact-key CSR offset
  }
  __syncthreads();
  if (m <= SCAP){
    #pragma unroll
    for (int r = 0; r < 30; ++r){
      if (px[r] >= 0){
        int p = atomicAdd(&rnk[(px[r] >> shift) - k0], 1);
        srt[p] = make_int2(px[r], py[r]);
      }
    }
    __syncthreads();
    for (int s = t; s < m; s += 256) pairs[r0 + s] = srt[s];
  } else {
    __syncthreads();
    for (int s = t; s < m; s += 256){
      int2 p = bounce[s];
      int q = atomicAdd(&rnk[(p.x >> shift) - k0], 1);
      pairs[r0 + q] = p;
    }
  }
}

// ---------------- per-edge reduce: T[e] = sum a*Xbf[v], B[e] = sum a ----------------
__global__ __launch_bounds__(128) void edge_reduce(
        const unsigned short* __restrict__ Xbf, const int* __restrict__ offE,
        const int2* __restrict__ PE,
        float* __restrict__ T, float* __restrict__ B){
  int e = blockIdx.x, d = threadIdx.x;
  int s0 = offE[e], s1 = offE[e+1];
  __shared__ int   vs[128];
  __shared__ float as[128];
  float acc = 0.f, bacc = 0.f;
  for (int base = s0; base < s1; base += 128){
    int L = min(128, s1 - base);
    __syncthreads();
    if (d < L){
      int2 p = PE[base + d];
      vs[d] = p.x & 0xFFFF; as[d] = __int_as_float(p.y);
    }
    __syncthreads();
    for (int j = 0; j < L; ++j){
      float a = as[j];
      acc  += a * bf2f(Xbf[(size_t)vs[j]*DIM + d]);
      bacc += a;
    }
  }
  T[(size_t)e*DIM + d] = acc;
  if (d == 0) B[e] = bacc;
}

// ---------------- Xe = T @ Wt1 + B*b1  (writes bf16 XEBF) ----------------
__global__ __launch_bounds__(256) void gemm_xe(const float* __restrict__ W1b,
                                               float* __restrict__ ws){
  __shared__ float Y[32][136];
  const float* T = ws + T_OFF;
  const float* Wt1 = ws + WT1_OFF;
  const float* Bs  = ws + B_OFF;
  unsigned short* Xe = (unsigned short*)(ws + XEBF_OFF);
  int n0 = blockIdx.x * 32;
  int tid = threadIdx.x;
  {
    int lr = tid >> 3, lj = tid & 7;
    int gn = n0 + lr; if (gn >= NEV) gn = NEV - 1;
    const float* src = T + (size_t)gn*DIM + lj*16;
    #pragma unroll
    for (int q = 0; q < 4; ++q)
      *(float4*)(&Y[lr][lj*16 + q*4]) = *(const float4*)(src + q*4);
  }
  __syncthreads();
  int rq = tid >> 5, cq = tid & 31;
  float acc[4][4];
  #pragma unroll
  for (int u=0;u<4;++u){ acc[u][0]=0;acc[u][1]=0;acc[u][2]=0;acc[u][3]=0; }
  const float* Crow = Wt1 + cq*4;
  #pragma unroll 4
  for (int k = 0; k < 128; ++k){
    float4 c = *(const float4*)(Crow + (size_t)k*128);
    #pragma unroll
    for (int u = 0; u < 4; ++u){
      float y = Y[rq*4 + u][k];
      acc[u][0] += y*c.x; acc[u][1] += y*c.y; acc[u][2] += y*c.z; acc[u][3] += y*c.w;
    }
  }
  float4 b1v = *(const float4*)(W1b + cq*4);
  #pragma unroll
  for (int u = 0; u < 4; ++u){
    int e = n0 + rq*4 + u;
    if (e < NEV){
      float Bv = Bs[e];
      ushort4 h;
      h.x = f2bf(acc[u][0] + Bv*b1v.x); h.y = f2bf(acc[u][1] + Bv*b1v.y);
      h.z = f2bf(acc[u][2] + Bv*b1v.z); h.w = f2bf(acc[u][3] + Bv*b1v.w);
      *(ushort4*)(Xe + (size_t)e*DIM + cq*4) = h;
    }
  }
}

// ---------------- per-vertex reduce: S2[v] = sum a*Xe[e] (into out), A[v] = sum a ----------------
__global__ __launch_bounds__(128) void vertex_reduce(
        const unsigned short* __restrict__ Xe, const int* __restrict__ offV,
        const int2* __restrict__ PV,
        float* __restrict__ S2, float* __restrict__ A){
  int v = blockIdx.x, d = threadIdx.x;
  int s0 = offV[v], s1 = offV[v+1];
  __shared__ int   es[128];
  __shared__ float as[128];
  float acc = 0.f, aacc = 0.f;
  for (int base = s0; base < s1; base += 128){
    int L = min(128, s1 - base);
    __syncthreads();
    if (d < L){
      int2 p = PV[base + d];
      es[d] = p.x & 0x3FFF; as[d] = __int_as_float(p.y);
    }
    __syncthreads();
    for (int j = 0; j < L; ++j){
      float a = as[j];
      acc  += a * bf2f(Xe[(size_t)es[j]*DIM + d]);
      aacc += a;
    }
  }
  S2[(size_t)v*DIM + d] = acc;
  if (d == 0) A[v] = aacc;
}

// ---------------- out = [A*X | S2 | X0] @ Ct + A*bA + Wb  via bf16 MFMA ----------------
#define LDS_STRIDE 392   // shorts per row: 384 + 8 pad

__global__ __launch_bounds__(256) void gemm_final_mfma(
        const float* __restrict__ X, const float* __restrict__ X0,
        const float* __restrict__ Wb, const float* __restrict__ ws,
        float* __restrict__ out){
  __shared__ unsigned short At[64 * LDS_STRIDE];
  __shared__ float ArS[64];
  const float* Aa = ws + A_OFF;
  const float* bA = ws + BA_OFF;
  const unsigned short* Bpack = (const unsigned short*)(ws + BPACK_OFF);
  int r0 = blockIdx.x * 64;
  int t = threadIdx.x;
  if (t < 64){
    int gn = r0 + t; if (gn >= NV) gn = NV - 1;
    ArS[t] = Aa[gn];
  }
  __syncthreads();
  #pragma unroll
  for (int seg = 0; seg < 3; ++seg){
    const float* src = (seg == 0) ? X : (seg == 1) ? out : X0;
    #pragma unroll
    for (int i = 0; i < 8; ++i){
      int idx = t + i*256;
      int row = idx >> 5;
      int c4  = idx & 31;
      int gn = r0 + row; if (gn >= NV) gn = NV - 1;
      float4 v = *(const float4*)(src + (size_t)gn*DIM + c4*4);
      if (seg == 0){
        float Ar = ArS[row];
        v.x *= Ar; v.y *= Ar; v.z *= Ar; v.w *= Ar;
      }
      ushort4 h;
      h.x = f2bf(v.x); h.y = f2bf(v.y); h.z = f2bf(v.z); h.w = f2bf(v.w);
      *(ushort4*)(&At[row*LDS_STRIDE + seg*128 + c4*4]) = h;
    }
  }
  __syncthreads();

  int w = t >> 6, l = t & 63;
  int m0 = w * 16;
  int lr = l & 15, lg = l >> 4;
  f32x4 acc[8];
  #pragma unroll
  for (int ct = 0; ct < 8; ++ct) acc[ct] = (f32x4){0.f,0.f,0.f,0.f};

  const unsigned short* arow = &At[(m0 + lr)*LDS_STRIDE + lg*8];
  for (int ks = 0; ks < 12; ++ks){
    bf16x8 af = *(const bf16x8*)(arow + ks*32);
    const bf16x8* bp = (const bf16x8*)(Bpack) + (size_t)ks*8*64 + l;
    #pragma unroll
    for (int ct = 0; ct < 8; ++ct){
      bf16x8 bf = bp[ct*64];
      acc[ct] = __builtin_amdgcn_mfma_f32_16x16x32_bf16(af, bf, acc[ct], 0, 0, 0);
    }
  }

  #pragma unroll
  for (int ct = 0; ct < 8; ++ct){
    int o = ct*16 + lr;
    float ba = bA[o], wb = Wb[o];
    #pragma unroll
    for (int r = 0; r < 4; ++r){
      int lrow = m0 + lg*4 + r;
      int row = r0 + lrow;
      if (row < NV){
        float Av = ArS[lrow];
        out[(size_t)row*DIM + o] = acc[ct][r] + Av*ba + wb;
      }
    }
  }
}

extern "C" void kernel_launch(void* const* d_in, const int* in_sizes, int n_in,
                              void* d_out, int out_size, void* d_ws, size_t ws_size,
                              hipStream_t stream){
  const float* X    = (const float*)d_in[0];
  const int*  vertex= (const int*)  d_in[1];
  const int*  edges = (const int*)  d_in[2];
  const float* X0   = (const float*)d_in[3];
  const float* alpha= (const float*)d_in[4];
  const float* W1w  = (const float*)d_in[5];
  const float* W1b  = (const float*)d_in[6];
  const float* W2w  = (const float*)d_in[7];
  const float* W2b  = (const float*)d_in[8];
  const float* Ww   = (const float*)d_in[9];
  const float* Wb   = (const float*)d_in[10];
  float* out = (float*)d_out;
  float* ws  = (float*)d_ws;

  int* bcntE = (int*)(ws + BCNTE_OFF);
  int* bOffE = (int*)(ws + BOFFE_OFF);
  int* bcntV = (int*)(ws + BCNTV_OFF);
  int* bOffV = (int*)(ws + BOFFV_OFF);
  int* offE  = (int*)(ws + OFFE_OFF);
  int* bcurE = (int*)(ws + CURE_OFF);
  int* offV  = (int*)(ws + OFFV_OFF);
  int* bcurV = (int*)(ws + CURV_OFF);
  int2* PV   = (int2*)(ws + PV_OFF);
  int2* PE   = (int2*)(out + PE_OUT_FLOAT_OFF);
  int2* bounce = (int2*)(ws + T_OFF);                   // sort fallback scratch
  unsigned short* Xbf  = (unsigned short*)out;          // front 12.8 MB of d_out
  unsigned short* Xebf = (unsigned short*)(ws + XEBF_OFF);

  hipMemsetAsync(ws + BCNTE_OFF, 0, 1024u * 4, stream); // zero bcnt/bOff block

  prep_weights <<<513, 128, 0, stream>>>(W1w, W2w, W2b, Ww, ws);
  count_bucket <<<(NNZV + 2047)/2048, 256, 0, stream>>>(vertex, edges, bcntE, bcntV);
  to_bf16      <<<(NV*DIM/8 + 255)/256, 256, 0, stream>>>(X, Xbf, NV*DIM/8);
  scan_buckets <<<1, 256, 0, stream>>>(bcntE, bcntV, bOffE, bOffV, bcurE, bcurV, offE, offV);
  fill_binned  <<<(NNZV + CHUNK - 1)/CHUNK, 256, 0, stream>>>(vertex, edges, alpha,
                                                              bcurE, PE, 1, NBKE);
  fill_binned  <<<(NNZV + CHUNK - 1)/CHUNK, 256, 0, stream>>>(vertex, edges, alpha,
                                                              bcurV, PV, 0, NBKV);
  sort_bucket  <<<NBKE, 256, 0, stream>>>(PE, bOffE, offE, bounce, 64,  16, NEV);
  sort_bucket  <<<NBKV, 256, 0, stream>>>(PV, bOffV, offV, bounce, 256, 14, NV);
  edge_reduce  <<<NEV, 128, 0, stream>>>(Xbf, offE, PE, ws + T_OFF, ws + B_OFF);
  gemm_xe      <<<(NEV + 31)/32, 256, 0, stream>>>(W1b, ws);
  vertex_reduce<<<NV, 128, 0, stream>>>(Xebf, offV, PV, out, ws + A_OFF);
  gemm_final_mfma<<<(NV + 63)/64, 256, 0, stream>>>(X, X0, Wb, ws, out);
}

// Round 10
// 203.726 us; speedup vs baseline: 3.4906x; 1.0076x over previous
//
#include <hip/hip_runtime.h>

#define NV   50000
#define NEV  10000
#define NNZV 600000
#define DIM  128

#define NBKE 157    // edge buckets: e>>6  (64 keys each)
#define NBKV 196    // vertex buckets: v>>8 (256 keys each)
#define CHUNK 4096
#define SCAP 7680

// workspace layout (float offsets) — total 3,401,920 floats = 13.6 MB (proven)
#define BPACK_OFF 0        // 16384: bf16 256x128 packed [C1;C3] (32768 ushorts)
#define WP_OFF    24576    // 16384: W'' = W1^T @ C2, f32 [k][o]
#define BA_OFF    40960    // 256: bA[0..128), b1C2[128..256)
#define A_OFF     41216    // 50048: per-vertex alpha sum
#define B_OFF     91264    // 10048: per-edge alpha sum
#define T_OFF     101312   // 1280000: f32 T; also C2tmp (prep) + int2 bounce (sort)
#define XEBF_OFF  1381312  // 640000 floats: bf16 Ye (1.28M ushort)
#define BCNTE_OFF 2021312  // int 256
#define BOFFE_OFF 2021568  // int 256
#define BCNTV_OFF 2021824  // int 256
#define BOFFV_OFF 2022080  // int 256
#define OFFE_OFF  2031328  // int 10016: exact-key CSR offsets (edges)
#define CURE_OFF  2041344  // int 10016 (bcurE uses first 157)
#define OFFV_OFF  2101376  // int 50016: exact-key CSR offsets (vertices)
#define CURV_OFF  2151392  // int 50016 (bcurV uses first 196)
#define PV_OFF    2201920  // int2 600000: (v<<14|e, alpha) grouped by vertex
// d_out timeline: Xbf (bf16 X, front 12.8MB) + PE pairs (int2 at float 3.2M) are
// written early, consumed by edge_reduce, then gemm_pq overwrites ALL of d_out
// with R rows; vertex_fused does thread-local read-modify-write of its own row.
#define PE_OUT_FLOAT_OFF 3200000

typedef __attribute__((ext_vector_type(8))) short bf16x8;
typedef __attribute__((ext_vector_type(4))) float f32x4;

__device__ __forceinline__ unsigned short f2bf(float x){
  unsigned u = __float_as_uint(x);
  u += 0x7fffu + ((u >> 16) & 1u);     // round-to-nearest-even
  return (unsigned short)(u >> 16);
}
__device__ __forceinline__ float bf2f(unsigned short h){
  return __uint_as_float((unsigned)h << 16);
}

// ---------------- zero the bucket-count block (replaces hipMemsetAsync) ----------------
__global__ __launch_bounds__(256) void zero_counts(int* __restrict__ p){
  int t = threadIdx.x;
  #pragma unroll
  for (int r = 0; r < 4; ++r) p[r*256 + t] = 0;
}

// ---------------- prep1: pack [C1;C3], compute C2tmp (f32), bA ----------------
__global__ __launch_bounds__(128) void prep1(
        const float* __restrict__ W2w, const float* __restrict__ W2b,
        const float* __restrict__ Ww, float* __restrict__ ws){
  int b = blockIdx.x, o = threadIdx.x;
  if (b < 256){
    float s;
    if (b < 128){            // C1[k=b][o] = 0.5*sum_m Ww[o][m]*W2w[m][b]  (X part)
      float acc = 0.f;
      for (int m = 0; m < 128; ++m) acc += Ww[o*128 + m] * W2w[m*256 + b];
      s = 0.5f * acc;
    } else {                 // C3[k=b-128][o] = 0.5*Ww[o][b-128]  (X0 part)
      s = 0.5f * Ww[o*128 + (b - 128)];
    }
    int ks = b >> 5, g = (b >> 3) & 3, j = b & 7;
    int ct = o >> 4, lo = o & 15;
    unsigned short* Bp = (unsigned short*)(ws + BPACK_OFF);
    Bp[((size_t)((ks*8 + ct)*64 + g*16 + lo))*8 + j] = f2bf(s);
  } else if (b < 384){       // C2tmp[m=b-256][o] = 0.5*sum_j Ww[o][j]*W2w[j][128+m]
    int m = b - 256;
    float acc = 0.f;
    for (int j = 0; j < 128; ++j) acc += Ww[o*128 + j] * W2w[j*256 + 128 + m];
    ws[T_OFF + m*128 + o] = 0.5f * acc;
  } else {                   // bA[o] = 0.5*sum_m Ww[o][m]*W2bias[m]
    float acc = 0.f;
    for (int m = 0; m < 128; ++m) acc += Ww[o*128 + m] * W2b[m];
    ws[BA_OFF + o] = 0.5f * acc;
  }
}

// ---------------- prep2: W''[k][o] = sum_m W1w[m][k]*C2tmp[m][o]; b1C2 ----------------
__global__ __launch_bounds__(128) void prep2(
        const float* __restrict__ W1w, const float* __restrict__ W1b,
        float* __restrict__ ws){
  int b = blockIdx.x, o = threadIdx.x;
  const float* C2t = ws + T_OFF;
  if (b < 128){
    float acc = 0.f;
    for (int m = 0; m < 128; ++m) acc += W1w[m*128 + b] * C2t[m*128 + o];
    ws[WP_OFF + b*128 + o] = acc;
  } else {
    float acc = 0.f;
    for (int m = 0; m < 128; ++m) acc += W1b[m] * C2t[m*128 + o];
    ws[BA_OFF + 128 + o] = acc;
  }
}

// ---------------- bucket-granularity histogram (LDS-aggregated) ----------------
__global__ __launch_bounds__(256) void count_bucket(
        const int* __restrict__ vertex, const int* __restrict__ edges,
        int* __restrict__ bcntE, int* __restrict__ bcntV){
  __shared__ int hE[256], hV[256];
  int t = threadIdx.x;
  hE[t] = 0; hV[t] = 0;
  __syncthreads();
  int i0 = blockIdx.x * 2048;
  #pragma unroll
  for (int r = 0; r < 8; ++r){
    int i = i0 + r*256 + t;
    if (i < NNZV){
      atomicAdd(&hE[edges[i]  >> 6], 1);
      atomicAdd(&hV[vertex[i] >> 8], 1);
    }
  }
  __syncthreads();
  if (hE[t]) atomicAdd(bcntE + t, hE[t]);
  if (hV[t]) atomicAdd(bcntV + t, hV[t]);
}

// ---------------- X -> bf16 copy (into d_out front) ----------------
__global__ __launch_bounds__(256) void to_bf16(
        const float* __restrict__ src, unsigned short* __restrict__ dst, int n8){
  int i = blockIdx.x*256 + threadIdx.x;
  if (i >= n8) return;
  float4 v0 = ((const float4*)src)[(size_t)i*2];
  float4 v1 = ((const float4*)src)[(size_t)i*2 + 1];
  ushort4 h0, h1;
  h0.x=f2bf(v0.x); h0.y=f2bf(v0.y); h0.z=f2bf(v0.z); h0.w=f2bf(v0.w);
  h1.x=f2bf(v1.x); h1.y=f2bf(v1.y); h1.z=f2bf(v1.z); h1.w=f2bf(v1.w);
  ((ushort4*)dst)[(size_t)i*2]     = h0;
  ((ushort4*)dst)[(size_t)i*2 + 1] = h1;
}

// ---------------- tiny: scan bucket counts, init cursors, set tail offs ----------------
__global__ __launch_bounds__(256) void scan_buckets(
        const int* __restrict__ bcntE, const int* __restrict__ bcntV,
        int* __restrict__ bOffE, int* __restrict__ bOffV,
        int* __restrict__ bcurE, int* __restrict__ bcurV,
        int* __restrict__ offE, int* __restrict__ offV){
  __shared__ int s[256];
  int t = threadIdx.x;
  int c = (t < NBKE) ? bcntE[t] : 0;
  s[t] = c; __syncthreads();
  for (int d = 1; d < 256; d <<= 1){
    int x = (t >= d) ? s[t-d] : 0;
    __syncthreads(); s[t] += x; __syncthreads();
  }
  if (t < NBKE){ bOffE[t] = s[t] - c; bcurE[t] = s[t] - c; }
  if (t == 0){ bOffE[NBKE] = NNZV; offE[NEV] = NNZV; }
  __syncthreads();
  int c2 = (t < NBKV) ? bcntV[t] : 0;
  s[t] = c2; __syncthreads();
  for (int d = 1; d < 256; d <<= 1){
    int x = (t >= d) ? s[t-d] : 0;
    __syncthreads(); s[t] += x; __syncthreads();
  }
  if (t < NBKV){ bOffV[t] = s[t] - c2; bcurV[t] = s[t] - c2; }
  if (t == 0){ bOffV[NBKV] = NNZV; offV[NV] = NNZV; }
}

// ---------------- pass 1: LDS-aggregated binning of (packed,alpha) pairs ----------------
__global__ __launch_bounds__(256) void fill_binned(
        const int* __restrict__ vertex, const int* __restrict__ edges,
        const float* __restrict__ alpha,
        int* __restrict__ bcur, int2* __restrict__ pairs,
        int isE, int nbk){
  __shared__ int hist[256], lofs[256], gbase[256], pos[256], ss[256];
  __shared__ int2 stage[CHUNK];
  int t = threadIdx.x;
  int i0 = blockIdx.x * CHUNK;
  if (t < nbk) hist[t] = 0;
  __syncthreads();
  int pk[16], pa[16], kb[16];
  #pragma unroll
  for (int r = 0; r < 16; ++r){
    int i = i0 + r*256 + t;
    int b = -1, packed = 0, ab = 0;
    if (i < NNZV){
      int v = vertex[i], e = edges[i];
      ab = __float_as_int(alpha[i]);
      packed = isE ? ((e << 16) | v) : ((v << 14) | e);
      b = packed >> 22;
      atomicAdd(&hist[b], 1);
    }
    pk[r] = packed; pa[r] = ab; kb[r] = b;
  }
  __syncthreads();
  int c = (t < nbk) ? hist[t] : 0;
  ss[t] = c; __syncthreads();
  for (int d = 1; d < 256; d <<= 1){
    int x = (t >= d) ? ss[t-d] : 0;
    __syncthreads(); ss[t] += x; __syncthreads();
  }
  if (t < nbk){ lofs[t] = ss[t] - c; pos[t] = ss[t] - c; }
  __syncthreads();
  #pragma unroll
  for (int r = 0; r < 16; ++r){
    if (kb[r] >= 0){
      int p = atomicAdd(&pos[kb[r]], 1);
      stage[p] = make_int2(pk[r], pa[r]);
    }
  }
  __syncthreads();
  if (t < nbk){
    int cnt = hist[t];
    gbase[t] = cnt ? atomicAdd(&bcur[t], cnt) : 0;
  }
  __syncthreads();
  int total = (i0 + CHUNK <= NNZV) ? CHUNK : (NNZV - i0);
  for (int s = t; s < total; s += 256){
    int lo = 0, hi = nbk - 1;
    while (lo < hi){ int mid = (lo + hi + 1) >> 1; if (lofs[mid] <= s) lo = mid; else hi = mid - 1; }
    pairs[gbase[lo] + (s - lofs[lo])] = stage[s];
  }
}

// ---------------- pass 2: in-bucket counting sort + exact-key off + alpha sums ----------------
__global__ __launch_bounds__(256) void sort_bucket(
        int2* __restrict__ pairs, const int* __restrict__ bOff,
        int* __restrict__ off, float* __restrict__ sums,
        int2* __restrict__ bounce, int kpb, int shift, int nkeys){
  int b = blockIdx.x, t = threadIdx.x;
  int k0 = b * kpb;
  int r0 = bOff[b], r1 = bOff[b+1];
  int m = r1 - r0;
  __shared__ int hist[256], rnk[256], ssc[256];
  __shared__ int2 srt[SCAP];
  for (int q = t; q < kpb; q += 256) hist[q] = 0;
  __syncthreads();
  int px[30], py[30];
  #pragma unroll
  for (int r = 0; r < 30; ++r){
    int s = r*256 + t;
    int x = -1, y = 0;
    if (s < m && m <= SCAP){
      int2 p = pairs[r0 + s];
      x = p.x; y = p.y;
      atomicAdd(&hist[(x >> shift) - k0], 1);
    }
    px[r] = x; py[r] = y;
  }
  if (m > SCAP){   // statistically never taken; correct fallback via global bounce
    for (int s = t; s < m; s += 256){
      int2 p = pairs[r0 + s];
      bounce[s] = p;
      atomicAdd(&hist[(p.x >> shift) - k0], 1);
    }
  }
  __syncthreads();
  int c = (t < kpb) ? hist[t] : 0;
  ssc[t] = c; __syncthreads();
  for (int d = 1; d < 256; d <<= 1){
    int x = (t >= d) ? ssc[t-d] : 0;
    __syncthreads(); ssc[t] += x; __syncthreads();
  }
  if (t < kpb){
    rnk[t] = ssc[t] - c;
    int k = k0 + t;
    if (k < nkeys) off[k] = r0 + ssc[t] - c;
  }
  __syncthreads();
  if (m <= SCAP){
    #pragma unroll
    for (int r = 0; r < 30; ++r){
      if (px[r] >= 0){
        int p = atomicAdd(&rnk[(px[r] >> shift) - k0], 1);
        srt[p] = make_int2(px[r], py[r]);
      }
    }
    __syncthreads();
    for (int s = t; s < m; s += 256) pairs[r0 + s] = srt[s];
    if (t < kpb){
      int k = k0 + t;
      if (k < nkeys){
        float sa = 0.f;
        int s0 = ssc[t] - hist[t], s1 = ssc[t];
        for (int s = s0; s < s1; ++s) sa += __int_as_float(srt[s].y);
        sums[k] = sa;
      }
    }
  } else {
    __syncthreads();
    for (int s = t; s < m; s += 256){
      int2 p = bounce[s];
      int q = atomicAdd(&rnk[(p.x >> shift) - k0], 1);
      pairs[r0 + q] = p;
    }
    __syncthreads();
    if (t < kpb){
      int k = k0 + t;
      if (k < nkeys){
        float sa = 0.f;
        int s0 = ssc[t] - hist[t], s1 = ssc[t];
        for (int s = s0; s < s1; ++s) sa += __int_as_float(pairs[r0 + s].y);
        sums[k] = sa;
      }
    }
  }
}

// ---------------- per-edge reduce: T[e] = sum a*Xbf[v] ----------------
__global__ __launch_bounds__(128) void edge_reduce(
        const unsigned short* __restrict__ Xbf, const int* __restrict__ offE,
        const int2* __restrict__ PE, float* __restrict__ T){
  int e = blockIdx.x, d = threadIdx.x;
  int s0 = offE[e], s1 = offE[e+1];
  __shared__ int   vs[128];
  __shared__ float as[128];
  float acc = 0.f;
  for (int base = s0; base < s1; base += 128){
    int L = min(128, s1 - base);
    __syncthreads();
    if (d < L){
      int2 p = PE[base + d];
      vs[d] = p.x & 0xFFFF; as[d] = __int_as_float(p.y);
    }
    __syncthreads();
    for (int j = 0; j < L; ++j)
      acc += as[j] * bf2f(Xbf[(size_t)vs[j]*DIM + d]);
  }
  T[(size_t)e*DIM + d] = acc;
}

// ---------------- Ye = T @ W'' + B*b1C2  (writes bf16 XEBF) ----------------
__global__ __launch_bounds__(256) void gemm_ye(float* __restrict__ ws){
  __shared__ float Y[32][136];
  const float* T   = ws + T_OFF;
  const float* WP  = ws + WP_OFF;
  const float* Bs  = ws + B_OFF;
  const float* b1p = ws + BA_OFF + 128;
  unsigned short* Ye = (unsigned short*)(ws + XEBF_OFF);
  int n0 = blockIdx.x * 32;
  int tid = threadIdx.x;
  {
    int lr = tid >> 3, lj = tid & 7;
    int gn = n0 + lr; if (gn >= NEV) gn = NEV - 1;
    const float* src = T + (size_t)gn*DIM + lj*16;
    #pragma unroll
    for (int q = 0; q < 4; ++q)
      *(float4*)(&Y[lr][lj*16 + q*4]) = *(const float4*)(src + q*4);
  }
  __syncthreads();
  int rq = tid >> 5, cq = tid & 31;
  float acc[4][4];
  #pragma unroll
  for (int u=0;u<4;++u){ acc[u][0]=0;acc[u][1]=0;acc[u][2]=0;acc[u][3]=0; }
  const float* Crow = WP + cq*4;
  #pragma unroll 4
  for (int k = 0; k < 128; ++k){
    float4 c = *(const float4*)(Crow + (size_t)k*128);
    #pragma unroll
    for (int u = 0; u < 4; ++u){
      float y = Y[rq*4 + u][k];
      acc[u][0] += y*c.x; acc[u][1] += y*c.y; acc[u][2] += y*c.z; acc[u][3] += y*c.w;
    }
  }
  float4 b1v = *(const float4*)(b1p + cq*4);
  #pragma unroll
  for (int u = 0; u < 4; ++u){
    int e = n0 + rq*4 + u;
    if (e < NEV){
      float Bv = Bs[e];
      ushort4 h;
      h.x = f2bf(acc[u][0] + Bv*b1v.x); h.y = f2bf(acc[u][1] + Bv*b1v.y);
      h.z = f2bf(acc[u][2] + Bv*b1v.z); h.w = f2bf(acc[u][3] + Bv*b1v.w);
      *(ushort4*)(Ye + (size_t)e*DIM + cq*4) = h;
    }
  }
}

// ---------------- R = [Av*X | X0] @ [C1;C3] + Av*bA + Wb  (writes d_out rows) ----------------
#define LDS_STRIDE 264   // shorts per row: 256 + 8 pad

__global__ __launch_bounds__(256) void gemm_pq(
        const float* __restrict__ X, const float* __restrict__ X0,
        const float* __restrict__ Wb, const float* __restrict__ ws,
        float* __restrict__ R){
  __shared__ unsigned short At[64 * LDS_STRIDE];
  __shared__ float ArS[64];
  const float* Aa = ws + A_OFF;
  const float* bA = ws + BA_OFF;
  const unsigned short* Bpack = (const unsigned short*)(ws + BPACK_OFF);
  int r0 = blockIdx.x * 64;
  int t = threadIdx.x;
  if (t < 64){
    int gn = r0 + t; if (gn >= NV) gn = NV - 1;
    ArS[t] = Aa[gn];
  }
  __syncthreads();
  #pragma unroll
  for (int seg = 0; seg < 2; ++seg){
    const float* src = (seg == 0) ? X : X0;
    #pragma unroll
    for (int i = 0; i < 8; ++i){
      int idx = t + i*256;
      int row = idx >> 5;
      int c4  = idx & 31;
      int gn = r0 + row; if (gn >= NV) gn = NV - 1;
      float4 v = *(const float4*)(src + (size_t)gn*DIM + c4*4);
      if (seg == 0){
        float Ar = ArS[row];
        v.x *= Ar; v.y *= Ar; v.z *= Ar; v.w *= Ar;
      }
      ushort4 h;
      h.x = f2bf(v.x); h.y = f2bf(v.y); h.z = f2bf(v.z); h.w = f2bf(v.w);
      *(ushort4*)(&At[row*LDS_STRIDE + seg*128 + c4*4]) = h;
    }
  }
  __syncthreads();

  int w = t >> 6, l = t & 63;
  int m0 = w * 16;
  int lr = l & 15, lg = l >> 4;
  f32x4 acc[8];
  #pragma unroll
  for (int ct = 0; ct < 8; ++ct) acc[ct] = (f32x4){0.f,0.f,0.f,0.f};

  const unsigned short* arow = &At[(m0 + lr)*LDS_STRIDE + lg*8];
  #pragma unroll
  for (int ks = 0; ks < 8; ++ks){
    bf16x8 af = *(const bf16x8*)(arow + ks*32);
    const bf16x8* bp = (const bf16x8*)(Bpack) + (size_t)ks*8*64 + l;
    #pragma unroll
    for (int ct = 0; ct < 8; ++ct){
      bf16x8 bf = bp[ct*64];
      acc[ct] = __builtin_amdgcn_mfma_f32_16x16x32_bf16(af, bf, acc[ct], 0, 0, 0);
    }
  }

  #pragma unroll
  for (int ct = 0; ct < 8; ++ct){
    int o = ct*16 + lr;
    float ba = bA[o], wb = Wb[o];
    #pragma unroll
    for (int r = 0; r < 4; ++r){
      int lrow = m0 + lg*4 + r;
      int row = r0 + lrow;
      if (row < NV){
        float Av = ArS[lrow];
        R[(size_t)row*DIM + o] = acc[ct][r] + Av*ba + wb;
      }
    }
  }
}

// ---------------- out[v] = R[v] + sum a*Ye[e]  (thread-local RMW of own row) ----------------
__global__ __launch_bounds__(128) void vertex_fused(
        const unsigned short* __restrict__ Ye, const int* __restrict__ offV,
        const int2* __restrict__ PV, float* __restrict__ out){
  int v = blockIdx.x, d = threadIdx.x;
  int s0 = offV[v], s1 = offV[v+1];
  __shared__ int   es[128];
  __shared__ float as[128];
  float acc = 0.f;
  for (int base = s0; base < s1; base += 128){
    int L = min(128, s1 - base);
    __syncthreads();
    if (d < L){
      int2 p = PV[base + d];
      es[d] = p.x & 0x3FFF; as[d] = __int_as_float(p.y);
    }
    __syncthreads();
    for (int j = 0; j < L; ++j)
      acc += as[j] * bf2f(Ye[(size_t)es[j]*DIM + d]);
  }
  out[(size_t)v*DIM + d] += acc;   // R already there; same thread, same address
}

extern "C" void kernel_launch(void* const* d_in, const int* in_sizes, int n_in,
                              void* d_out, int out_size, void* d_ws, size_t ws_size,
                              hipStream_t stream){
  const float* X    = (const float*)d_in[0];
  const int*  vertex= (const int*)  d_in[1];
  const int*  edges = (const int*)  d_in[2];
  const float* X0   = (const float*)d_in[3];
  const float* alpha= (const float*)d_in[4];
  const float* W1w  = (const float*)d_in[5];
  const float* W1b  = (const float*)d_in[6];
  const float* W2w  = (const float*)d_in[7];
  const float* W2b  = (const float*)d_in[8];
  const float* Ww   = (const float*)d_in[9];
  const float* Wb   = (const float*)d_in[10];
  float* out = (float*)d_out;
  float* ws  = (float*)d_ws;

  int* bcntE = (int*)(ws + BCNTE_OFF);
  int* bOffE = (int*)(ws + BOFFE_OFF);
  int* bcntV = (int*)(ws + BCNTV_OFF);
  int* bOffV = (int*)(ws + BOFFV_OFF);
  int* offE  = (int*)(ws + OFFE_OFF);
  int* bcurE = (int*)(ws + CURE_OFF);
  int* offV  = (int*)(ws + OFFV_OFF);
  int* bcurV = (int*)(ws + CURV_OFF);
  int2* PV   = (int2*)(ws + PV_OFF);
  int2* PE   = (int2*)(out + PE_OUT_FLOAT_OFF);
  int2* bounce = (int2*)(ws + T_OFF);
  unsigned short* Xbf = (unsigned short*)out;           // front 12.8 MB of d_out
  unsigned short* Ye  = (unsigned short*)(ws + XEBF_OFF);

  zero_counts  <<<1, 256, 0, stream>>>(bcntE);
  prep1        <<<385, 128, 0, stream>>>(W2w, W2b, Ww, ws);
  prep2        <<<129, 128, 0, stream>>>(W1w, W1b, ws);
  count_bucket <<<(NNZV + 2047)/2048, 256, 0, stream>>>(vertex, edges, bcntE, bcntV);
  to_bf16      <<<(NV*DIM/8 + 255)/256, 256, 0, stream>>>(X, Xbf, NV*DIM/8);
  scan_buckets <<<1, 256, 0, stream>>>(bcntE, bcntV, bOffE, bOffV, bcurE, bcurV, offE, offV);
  fill_binned  <<<(NNZV + CHUNK - 1)/CHUNK, 256, 0, stream>>>(vertex, edges, alpha,
                                                              bcurE, PE, 1, NBKE);
  fill_binned  <<<(NNZV + CHUNK - 1)/CHUNK, 256, 0, stream>>>(vertex, edges, alpha,
                                                              bcurV, PV, 0, NBKV);
  sort_bucket  <<<NBKE, 256, 0, stream>>>(PE, bOffE, offE, ws + B_OFF, bounce, 64,  16, NEV);
  sort_bucket  <<<NBKV, 256, 0, stream>>>(PV, bOffV, offV, ws + A_OFF, bounce, 256, 14, NV);
  edge_reduce  <<<NEV, 128, 0, stream>>>(Xbf, offE, PE, ws + T_OFF);
  gemm_ye      <<<(NEV + 31)/32, 256, 0, stream>>>(ws);
  gemm_pq      <<<(NV + 63)/64, 256, 0, stream>>>(X, X0, Wb, ws, out);
  vertex_fused <<<NV, 128, 0, stream>>>(Ye, offV, PV, out);
}

// Round 11
// 189.176 us; speedup vs baseline: 3.7591x; 1.0769x over previous
//
#include <hip/hip_runtime.h>

#define NV   50000
#define NEV  10000
#define NNZV 600000
#define DIM  128

#define NBKE 157    // edge buckets: e>>6  (64 keys each)
#define NBKV 196    // vertex buckets: v>>8 (256 keys each)
#define CH2  2048   // fused fill chunk
#define SCAP 7680

// workspace layout (float offsets) — total 3,401,920 floats = 13.6 MB (proven)
#define BPACK_OFF 0        // 16384: bf16 256x128 packed [C1;C3] (32768 ushorts)
#define WP_OFF    24576    // 16384: W'' = W1^T @ C2, f32 [k][o]
#define BA_OFF    40960    // 256: bA[0..128), b1C2[128..256)
#define A_OFF     41216    // 50048: per-vertex alpha sum
#define B_OFF     91264    // 10048: per-edge alpha sum
#define T_OFF     101312   // 1280000: f32 T; also C2tmp (prep) + int2 bounce (sort)
#define XEBF_OFF  1381312  // 640000 floats: bf16 Ye (1.28M ushort)
#define BCNTE_OFF 2021312  // int 256
#define BOFFE_OFF 2021568  // int 256
#define BCNTV_OFF 2021824  // int 256
#define BOFFV_OFF 2022080  // int 256
#define OFFE_OFF  2031328  // int 10016: exact-key CSR offsets (edges)
#define CURE_OFF  2041344  // int 10016 (bcurE uses first 157)
#define OFFV_OFF  2101376  // int 50016: exact-key CSR offsets (vertices)
#define CURV_OFF  2151392  // int 50016 (bcurV uses first 196)
#define PV_OFF    2201920  // int2 600000: (v<<14|e, alpha) grouped by vertex
// d_out timeline: Xbf (bf16 X, front 12.8MB) + PE pairs (int2 at float 3.2M) are
// written early, consumed by edge_reduce, then gemm_pq overwrites ALL of d_out
// with R rows; vertex_fused does wave-local read-modify-write of its own row.
#define PE_OUT_FLOAT_OFF 3200000

typedef __attribute__((ext_vector_type(8))) short bf16x8;
typedef __attribute__((ext_vector_type(4))) float f32x4;

__device__ __forceinline__ unsigned short f2bf(float x){
  unsigned u = __float_as_uint(x);
  u += 0x7fffu + ((u >> 16) & 1u);     // round-to-nearest-even
  return (unsigned short)(u >> 16);
}
__device__ __forceinline__ float bf2f(unsigned short h){
  return __uint_as_float((unsigned)h << 16);
}

// ---------------- zero the bucket-count block ----------------
__global__ __launch_bounds__(256) void zero_counts(int* __restrict__ p){
  int t = threadIdx.x;
  #pragma unroll
  for (int r = 0; r < 4; ++r) p[r*256 + t] = 0;
}

// ---------------- prep1: pack [C1;C3], compute C2tmp (f32), bA ----------------
__global__ __launch_bounds__(128) void prep1(
        const float* __restrict__ W2w, const float* __restrict__ W2b,
        const float* __restrict__ Ww, float* __restrict__ ws){
  int b = blockIdx.x, o = threadIdx.x;
  if (b < 256){
    float s;
    if (b < 128){            // C1[k=b][o] = 0.5*sum_m Ww[o][m]*W2w[m][b]
      float acc = 0.f;
      for (int m = 0; m < 128; ++m) acc += Ww[o*128 + m] * W2w[m*256 + b];
      s = 0.5f * acc;
    } else {                 // C3[k=b-128][o] = 0.5*Ww[o][b-128]
      s = 0.5f * Ww[o*128 + (b - 128)];
    }
    int ks = b >> 5, g = (b >> 3) & 3, j = b & 7;
    int ct = o >> 4, lo = o & 15;
    unsigned short* Bp = (unsigned short*)(ws + BPACK_OFF);
    Bp[((size_t)((ks*8 + ct)*64 + g*16 + lo))*8 + j] = f2bf(s);
  } else if (b < 384){       // C2tmp[m][o]
    int m = b - 256;
    float acc = 0.f;
    for (int j = 0; j < 128; ++j) acc += Ww[o*128 + j] * W2w[j*256 + 128 + m];
    ws[T_OFF + m*128 + o] = 0.5f * acc;
  } else {                   // bA
    float acc = 0.f;
    for (int m = 0; m < 128; ++m) acc += Ww[o*128 + m] * W2b[m];
    ws[BA_OFF + o] = 0.5f * acc;
  }
}

// ---------------- prep2: W'' = W1^T @ C2tmp; b1C2 ----------------
__global__ __launch_bounds__(128) void prep2(
        const float* __restrict__ W1w, const float* __restrict__ W1b,
        float* __restrict__ ws){
  int b = blockIdx.x, o = threadIdx.x;
  const float* C2t = ws + T_OFF;
  if (b < 128){
    float acc = 0.f;
    for (int m = 0; m < 128; ++m) acc += W1w[m*128 + b] * C2t[m*128 + o];
    ws[WP_OFF + b*128 + o] = acc;
  } else {
    float acc = 0.f;
    for (int m = 0; m < 128; ++m) acc += W1b[m] * C2t[m*128 + o];
    ws[BA_OFF + 128 + o] = acc;
  }
}

// ---------------- bucket-granularity histogram (LDS-aggregated) ----------------
__global__ __launch_bounds__(256) void count_bucket(
        const int* __restrict__ vertex, const int* __restrict__ edges,
        int* __restrict__ bcntE, int* __restrict__ bcntV){
  __shared__ int hE[256], hV[256];
  int t = threadIdx.x;
  hE[t] = 0; hV[t] = 0;
  __syncthreads();
  int i0 = blockIdx.x * 2048;
  #pragma unroll
  for (int r = 0; r < 8; ++r){
    int i = i0 + r*256 + t;
    if (i < NNZV){
      atomicAdd(&hE[edges[i]  >> 6], 1);
      atomicAdd(&hV[vertex[i] >> 8], 1);
    }
  }
  __syncthreads();
  if (hE[t]) atomicAdd(bcntE + t, hE[t]);
  if (hV[t]) atomicAdd(bcntV + t, hV[t]);
}

// ---------------- X -> bf16 copy (into d_out front) ----------------
__global__ __launch_bounds__(256) void to_bf16(
        const float* __restrict__ src, unsigned short* __restrict__ dst, int n8){
  int i = blockIdx.x*256 + threadIdx.x;
  if (i >= n8) return;
  float4 v0 = ((const float4*)src)[(size_t)i*2];
  float4 v1 = ((const float4*)src)[(size_t)i*2 + 1];
  ushort4 h0, h1;
  h0.x=f2bf(v0.x); h0.y=f2bf(v0.y); h0.z=f2bf(v0.z); h0.w=f2bf(v0.w);
  h1.x=f2bf(v1.x); h1.y=f2bf(v1.y); h1.z=f2bf(v1.z); h1.w=f2bf(v1.w);
  ((ushort4*)dst)[(size_t)i*2]     = h0;
  ((ushort4*)dst)[(size_t)i*2 + 1] = h1;
}

// ---------------- tiny: scan bucket counts, init cursors, set tail offs ----------------
__global__ __launch_bounds__(256) void scan_buckets(
        const int* __restrict__ bcntE, const int* __restrict__ bcntV,
        int* __restrict__ bOffE, int* __restrict__ bOffV,
        int* __restrict__ bcurE, int* __restrict__ bcurV,
        int* __restrict__ offE, int* __restrict__ offV){
  __shared__ int s[256];
  int t = threadIdx.x;
  int c = (t < NBKE) ? bcntE[t] : 0;
  s[t] = c; __syncthreads();
  for (int d = 1; d < 256; d <<= 1){
    int x = (t >= d) ? s[t-d] : 0;
    __syncthreads(); s[t] += x; __syncthreads();
  }
  if (t < NBKE){ bOffE[t] = s[t] - c; bcurE[t] = s[t] - c; }
  if (t == 0){ bOffE[NBKE] = NNZV; offE[NEV] = NNZV; }
  __syncthreads();
  int c2 = (t < NBKV) ? bcntV[t] : 0;
  s[t] = c2; __syncthreads();
  for (int d = 1; d < 256; d <<= 1){
    int x = (t >= d) ? s[t-d] : 0;
    __syncthreads(); s[t] += x; __syncthreads();
  }
  if (t < NBKV){ bOffV[t] = s[t] - c2; bcurV[t] = s[t] - c2; }
  if (t == 0){ bOffV[NBKV] = NNZV; offV[NV] = NNZV; }
}

// ---------------- fused binning: one pass produces PE and PV ----------------
__global__ __launch_bounds__(256) void fill_binned2(
        const int* __restrict__ vertex, const int* __restrict__ edges,
        const float* __restrict__ alpha,
        int* __restrict__ bcurE, int* __restrict__ bcurV,
        int2* __restrict__ PE, int2* __restrict__ PV){
  __shared__ int histE[256], lofsE[256], gbaseE[256], posE[256];
  __shared__ int histV[256], lofsV[256], gbaseV[256], posV[256];
  __shared__ int ss[256];
  __shared__ int2 stgE[CH2], stgV[CH2];
  int t = threadIdx.x;
  int i0 = blockIdx.x * CH2;
  histE[t] = 0; histV[t] = 0;
  __syncthreads();
  int pkE[8], pkV[8], pa[8];
  #pragma unroll
  for (int r = 0; r < 8; ++r){
    int i = i0 + r*256 + t;
    int pe = -1, pv = -1, ab = 0;
    if (i < NNZV){
      int v = vertex[i], e = edges[i];
      ab = __float_as_int(alpha[i]);
      pe = (e << 16) | v;              // pe>>22 == e>>6
      pv = (v << 14) | e;              // pv>>22 == v>>8
      atomicAdd(&histE[pe >> 22], 1);
      atomicAdd(&histV[pv >> 22], 1);
    }
    pkE[r] = pe; pkV[r] = pv; pa[r] = ab;
  }
  __syncthreads();
  int cE = histE[t];
  ss[t] = cE; __syncthreads();
  for (int d = 1; d < 256; d <<= 1){
    int x = (t >= d) ? ss[t-d] : 0;
    __syncthreads(); ss[t] += x; __syncthreads();
  }
  lofsE[t] = ss[t] - cE; posE[t] = ss[t] - cE;
  __syncthreads();
  int cV = histV[t];
  ss[t] = cV; __syncthreads();
  for (int d = 1; d < 256; d <<= 1){
    int x = (t >= d) ? ss[t-d] : 0;
    __syncthreads(); ss[t] += x; __syncthreads();
  }
  lofsV[t] = ss[t] - cV; posV[t] = ss[t] - cV;
  __syncthreads();
  #pragma unroll
  for (int r = 0; r < 8; ++r){
    if (pkE[r] != -1){
      int p = atomicAdd(&posE[pkE[r] >> 22], 1);
      stgE[p] = make_int2(pkE[r], pa[r]);
      int q = atomicAdd(&posV[pkV[r] >> 22], 1);
      stgV[q] = make_int2(pkV[r], pa[r]);
    }
  }
  __syncthreads();
  {
    int cnt = histE[t];
    gbaseE[t] = cnt ? atomicAdd(&bcurE[t], cnt) : 0;
    int cnt2 = histV[t];
    gbaseV[t] = cnt2 ? atomicAdd(&bcurV[t], cnt2) : 0;
  }
  __syncthreads();
  int total = min(CH2, NNZV - i0);
  for (int s = t; s < total; s += 256){
    int lo = 0, hi = NBKE - 1;
    while (lo < hi){ int mid = (lo + hi + 1) >> 1; if (lofsE[mid] <= s) lo = mid; else hi = mid - 1; }
    PE[gbaseE[lo] + (s - lofsE[lo])] = stgE[s];
    lo = 0; hi = NBKV - 1;
    while (lo < hi){ int mid = (lo + hi + 1) >> 1; if (lofsV[mid] <= s) lo = mid; else hi = mid - 1; }
    PV[gbaseV[lo] + (s - lofsV[lo])] = stgV[s];
  }
}

// ---------------- pass 2: in-bucket counting sort + exact-key off + alpha sums ----------------
__global__ __launch_bounds__(256) void sort_bucket(
        int2* __restrict__ pairs, const int* __restrict__ bOff,
        int* __restrict__ off, float* __restrict__ sums,
        int2* __restrict__ bounce, int kpb, int shift, int nkeys){
  int b = blockIdx.x, t = threadIdx.x;
  int k0 = b * kpb;
  int r0 = bOff[b], r1 = bOff[b+1];
  int m = r1 - r0;
  __shared__ int hist[256], rnk[256], ssc[256];
  __shared__ int2 srt[SCAP];
  for (int q = t; q < kpb; q += 256) hist[q] = 0;
  __syncthreads();
  int px[30], py[30];
  #pragma unroll
  for (int r = 0; r < 30; ++r){
    int s = r*256 + t;
    int x = -1, y = 0;
    if (s < m && m <= SCAP){
      int2 p = pairs[r0 + s];
      x = p.x; y = p.y;
      atomicAdd(&hist[(x >> shift) - k0], 1);
    }
    px[r] = x; py[r] = y;
  }
  if (m > SCAP){   // statistically never taken; correct fallback via global bounce
    for (int s = t; s < m; s += 256){
      int2 p = pairs[r0 + s];
      bounce[s] = p;
      atomicAdd(&hist[(p.x >> shift) - k0], 1);
    }
  }
  __syncthreads();
  int c = (t < kpb) ? hist[t] : 0;
  ssc[t] = c; __syncthreads();
  for (int d = 1; d < 256; d <<= 1){
    int x = (t >= d) ? ssc[t-d] : 0;
    __syncthreads(); ssc[t] += x; __syncthreads();
  }
  if (t < kpb){
    rnk[t] = ssc[t] - c;
    int k = k0 + t;
    if (k < nkeys) off[k] = r0 + ssc[t] - c;
  }
  __syncthreads();
  if (m <= SCAP){
    #pragma unroll
    for (int r = 0; r < 30; ++r){
      if (px[r] >= 0){
        int p = atomicAdd(&rnk[(px[r] >> shift) - k0], 1);
        srt[p] = make_int2(px[r], py[r]);
      }
    }
    __syncthreads();
    for (int s = t; s < m; s += 256) pairs[r0 + s] = srt[s];
    if (t < kpb){
      int k = k0 + t;
      if (k < nkeys){
        float sa = 0.f;
        int s0 = ssc[t] - hist[t], s1 = ssc[t];
        for (int s = s0; s < s1; ++s) sa += __int_as_float(srt[s].y);
        sums[k] = sa;
      }
    }
  } else {
    __syncthreads();
    for (int s = t; s < m; s += 256){
      int2 p = bounce[s];
      int q = atomicAdd(&rnk[(p.x >> shift) - k0], 1);
      pairs[r0 + q] = p;
    }
    __syncthreads();
    if (t < kpb){
      int k = k0 + t;
      if (k < nkeys){
        float sa = 0.f;
        int s0 = ssc[t] - hist[t], s1 = ssc[t];
        for (int s = s0; s < s1; ++s) sa += __int_as_float(pairs[r0 + s].y);
        sums[k] = sa;
      }
    }
  }
}

// ---------------- wave-per-edge reduce: T[e] = sum a*Xbf[v]  (barrier-free) ----------------
__global__ __launch_bounds__(256) void edge_reduce(
        const unsigned short* __restrict__ Xbf, const int* __restrict__ offE,
        const int2* __restrict__ PE, float* __restrict__ T){
  int w = threadIdx.x >> 6, l = threadIdx.x & 63;
  int e = blockIdx.x*4 + w;
  int s0 = offE[e], s1 = offE[e+1];
  float acc0 = 0.f, acc1 = 0.f;
  int j = s0;
  for (; j + 4 <= s1; j += 4){
    int2 p0 = PE[j], p1 = PE[j+1], p2 = PE[j+2], p3 = PE[j+3];
    int v0 = (p0.x & 0xFFFF) << 7, v1 = (p1.x & 0xFFFF) << 7;
    int v2 = (p2.x & 0xFFFF) << 7, v3 = (p3.x & 0xFFFF) << 7;
    float x00 = bf2f(Xbf[v0 + l]),      x01 = bf2f(Xbf[v0 + 64 + l]);
    float x10 = bf2f(Xbf[v1 + l]),      x11 = bf2f(Xbf[v1 + 64 + l]);
    float x20 = bf2f(Xbf[v2 + l]),      x21 = bf2f(Xbf[v2 + 64 + l]);
    float x30 = bf2f(Xbf[v3 + l]),      x31 = bf2f(Xbf[v3 + 64 + l]);
    float a0 = __int_as_float(p0.y), a1 = __int_as_float(p1.y);
    float a2 = __int_as_float(p2.y), a3 = __int_as_float(p3.y);
    acc0 += a0*x00 + a1*x10 + a2*x20 + a3*x30;
    acc1 += a0*x01 + a1*x11 + a2*x21 + a3*x31;
  }
  for (; j < s1; ++j){
    int2 p = PE[j];
    int v = (p.x & 0xFFFF) << 7;
    float a = __int_as_float(p.y);
    acc0 += a * bf2f(Xbf[v + l]);
    acc1 += a * bf2f(Xbf[v + 64 + l]);
  }
  size_t o = (size_t)e * DIM;
  T[o + l]      = acc0;
  T[o + 64 + l] = acc1;
}

// ---------------- Ye = T @ W'' + B*b1C2  (writes bf16 XEBF) ----------------
__global__ __launch_bounds__(256) void gemm_ye(float* __restrict__ ws){
  __shared__ float Y[32][136];
  const float* T   = ws + T_OFF;
  const float* WP  = ws + WP_OFF;
  const float* Bs  = ws + B_OFF;
  const float* b1p = ws + BA_OFF + 128;
  unsigned short* Ye = (unsigned short*)(ws + XEBF_OFF);
  int n0 = blockIdx.x * 32;
  int tid = threadIdx.x;
  {
    int lr = tid >> 3, lj = tid & 7;
    int gn = n0 + lr; if (gn >= NEV) gn = NEV - 1;
    const float* src = T + (size_t)gn*DIM + lj*16;
    #pragma unroll
    for (int q = 0; q < 4; ++q)
      *(float4*)(&Y[lr][lj*16 + q*4]) = *(const float4*)(src + q*4);
  }
  __syncthreads();
  int rq = tid >> 5, cq = tid & 31;
  float acc[4][4];
  #pragma unroll
  for (int u=0;u<4;++u){ acc[u][0]=0;acc[u][1]=0;acc[u][2]=0;acc[u][3]=0; }
  const float* Crow = WP + cq*4;
  #pragma unroll 4
  for (int k = 0; k < 128; ++k){
    float4 c = *(const float4*)(Crow + (size_t)k*128);
    #pragma unroll
    for (int u = 0; u < 4; ++u){
      float y = Y[rq*4 + u][k];
      acc[u][0] += y*c.x; acc[u][1] += y*c.y; acc[u][2] += y*c.z; acc[u][3] += y*c.w;
    }
  }
  float4 b1v = *(const float4*)(b1p + cq*4);
  #pragma unroll
  for (int u = 0; u < 4; ++u){
    int e = n0 + rq*4 + u;
    if (e < NEV){
      float Bv = Bs[e];
      ushort4 h;
      h.x = f2bf(acc[u][0] + Bv*b1v.x); h.y = f2bf(acc[u][1] + Bv*b1v.y);
      h.z = f2bf(acc[u][2] + Bv*b1v.z); h.w = f2bf(acc[u][3] + Bv*b1v.w);
      *(ushort4*)(Ye + (size_t)e*DIM + cq*4) = h;
    }
  }
}

// ---------------- R = [Av*X | X0] @ [C1;C3] + Av*bA + Wb  (writes d_out rows) ----------------
#define LDS_STRIDE 264   // shorts per row: 256 + 8 pad

__global__ __launch_bounds__(256) void gemm_pq(
        const float* __restrict__ X, const float* __restrict__ X0,
        const float* __restrict__ Wb, const float* __restrict__ ws,
        float* __restrict__ R){
  __shared__ unsigned short At[64 * LDS_STRIDE];
  __shared__ float ArS[64];
  const float* Aa = ws + A_OFF;
  const float* bA = ws + BA_OFF;
  const unsigned short* Bpack = (const unsigned short*)(ws + BPACK_OFF);
  int r0 = blockIdx.x * 64;
  int t = threadIdx.x;
  if (t < 64){
    int gn = r0 + t; if (gn >= NV) gn = NV - 1;
    ArS[t] = Aa[gn];
  }
  __syncthreads();
  #pragma unroll
  for (int seg = 0; seg < 2; ++seg){
    const float* src = (seg == 0) ? X : X0;
    #pragma unroll
    for (int i = 0; i < 8; ++i){
      int idx = t + i*256;
      int row = idx >> 5;
      int c4  = idx & 31;
      int gn = r0 + row; if (gn >= NV) gn = NV - 1;
      float4 v = *(const float4*)(src + (size_t)gn*DIM + c4*4);
      if (seg == 0){
        float Ar = ArS[row];
        v.x *= Ar; v.y *= Ar; v.z *= Ar; v.w *= Ar;
      }
      ushort4 h;
      h.x = f2bf(v.x); h.y = f2bf(v.y); h.z = f2bf(v.z); h.w = f2bf(v.w);
      *(ushort4*)(&At[row*LDS_STRIDE + seg*128 + c4*4]) = h;
    }
  }
  __syncthreads();

  int w = t >> 6, l = t & 63;
  int m0 = w * 16;
  int lr = l & 15, lg = l >> 4;
  f32x4 acc[8];
  #pragma unroll
  for (int ct = 0; ct < 8; ++ct) acc[ct] = (f32x4){0.f,0.f,0.f,0.f};

  const unsigned short* arow = &At[(m0 + lr)*LDS_STRIDE + lg*8];
  #pragma unroll
  for (int ks = 0; ks < 8; ++ks){
    bf16x8 af = *(const bf16x8*)(arow + ks*32);
    const bf16x8* bp = (const bf16x8*)(Bpack) + (size_t)ks*8*64 + l;
    #pragma unroll
    for (int ct = 0; ct < 8; ++ct){
      bf16x8 bf = bp[ct*64];
      acc[ct] = __builtin_amdgcn_mfma_f32_16x16x32_bf16(af, bf, acc[ct], 0, 0, 0);
    }
  }

  #pragma unroll
  for (int ct = 0; ct < 8; ++ct){
    int o = ct*16 + lr;
    float ba = bA[o], wb = Wb[o];
    #pragma unroll
    for (int r = 0; r < 4; ++r){
      int lrow = m0 + lg*4 + r;
      int row = r0 + lrow;
      if (row < NV){
        float Av = ArS[lrow];
        R[(size_t)row*DIM + o] = acc[ct][r] + Av*ba + wb;
      }
    }
  }
}

// ---------------- wave-per-vertex: out[v] += sum a*Ye[e]  (barrier-free) ----------------
__global__ __launch_bounds__(256) void vertex_fused(
        const unsigned short* __restrict__ Ye, const int* __restrict__ offV,
        const int2* __restrict__ PV, float* __restrict__ out){
  int w = threadIdx.x >> 6, l = threadIdx.x & 63;
  int v = blockIdx.x*4 + w;
  int s0 = offV[v], s1 = offV[v+1];
  float acc0 = 0.f, acc1 = 0.f;
  int j = s0;
  for (; j + 4 <= s1; j += 4){
    int2 p0 = PV[j], p1 = PV[j+1], p2 = PV[j+2], p3 = PV[j+3];
    int e0 = (p0.x & 0x3FFF) << 7, e1 = (p1.x & 0x3FFF) << 7;
    int e2 = (p2.x & 0x3FFF) << 7, e3 = (p3.x & 0x3FFF) << 7;
    float y00 = bf2f(Ye[e0 + l]),      y01 = bf2f(Ye[e0 + 64 + l]);
    float y10 = bf2f(Ye[e1 + l]),      y11 = bf2f(Ye[e1 + 64 + l]);
    float y20 = bf2f(Ye[e2 + l]),      y21 = bf2f(Ye[e2 + 64 + l]);
    float y30 = bf2f(Ye[e3 + l]),      y31 = bf2f(Ye[e3 + 64 + l]);
    float a0 = __int_as_float(p0.y), a1 = __int_as_float(p1.y);
    float a2 = __int_as_float(p2.y), a3 = __int_as_float(p3.y);
    acc0 += a0*y00 + a1*y10 + a2*y20 + a3*y30;
    acc1 += a0*y01 + a1*y11 + a2*y21 + a3*y31;
  }
  for (; j < s1; ++j){
    int2 p = PV[j];
    int e = (p.x & 0x3FFF) << 7;
    float a = __int_as_float(p.y);
    acc0 += a * bf2f(Ye[e + l]);
    acc1 += a * bf2f(Ye[e + 64 + l]);
  }
  size_t o = (size_t)v * DIM;
  out[o + l]      += acc0;   // R already there; same thread, same address
  out[o + 64 + l] += acc1;
}

extern "C" void kernel_launch(void* const* d_in, const int* in_sizes, int n_in,
                              void* d_out, int out_size, void* d_ws, size_t ws_size,
                              hipStream_t stream){
  const float* X    = (const float*)d_in[0];
  const int*  vertex= (const int*)  d_in[1];
  const int*  edges = (const int*)  d_in[2];
  const float* X0   = (const float*)d_in[3];
  const float* alpha= (const float*)d_in[4];
  const float* W1w  = (const float*)d_in[5];
  const float* W1b  = (const float*)d_in[6];
  const float* W2w  = (const float*)d_in[7];
  const float* W2b  = (const float*)d_in[8];
  const float* Ww   = (const float*)d_in[9];
  const float* Wb   = (const float*)d_in[10];
  float* out = (float*)d_out;
  float* ws  = (float*)d_ws;

  int* bcntE = (int*)(ws + BCNTE_OFF);
  int* bOffE = (int*)(ws + BOFFE_OFF);
  int* bcntV = (int*)(ws + BCNTV_OFF);
  int* bOffV = (int*)(ws + BOFFV_OFF);
  int* offE  = (int*)(ws + OFFE_OFF);
  int* bcurE = (int*)(ws + CURE_OFF);
  int* offV  = (int*)(ws + OFFV_OFF);
  int* bcurV = (int*)(ws + CURV_OFF);
  int2* PV   = (int2*)(ws + PV_OFF);
  int2* PE   = (int2*)(out + PE_OUT_FLOAT_OFF);
  int2* bounce = (int2*)(ws + T_OFF);
  unsigned short* Xbf = (unsigned short*)out;           // front 12.8 MB of d_out
  unsigned short* Ye  = (unsigned short*)(ws + XEBF_OFF);

  zero_counts  <<<1, 256, 0, stream>>>(bcntE);
  prep1        <<<385, 128, 0, stream>>>(W2w, W2b, Ww, ws);
  prep2        <<<129, 128, 0, stream>>>(W1w, W1b, ws);
  count_bucket <<<(NNZV + 2047)/2048, 256, 0, stream>>>(vertex, edges, bcntE, bcntV);
  to_bf16      <<<(NV*DIM/8 + 255)/256, 256, 0, stream>>>(X, Xbf, NV*DIM/8);
  scan_buckets <<<1, 256, 0, stream>>>(bcntE, bcntV, bOffE, bOffV, bcurE, bcurV, offE, offV);
  fill_binned2 <<<(NNZV + CH2 - 1)/CH2, 256, 0, stream>>>(vertex, edges, alpha,
                                                          bcurE, bcurV, PE, PV);
  sort_bucket  <<<NBKE, 256, 0, stream>>>(PE, bOffE, offE, ws + B_OFF, bounce, 64,  16, NEV);
  sort_bucket  <<<NBKV, 256, 0, stream>>>(PV, bOffV, offV, ws + A_OFF, bounce, 256, 14, NV);
  edge_reduce  <<<NEV/4, 256, 0, stream>>>(Xbf, offE, PE, ws + T_OFF);
  gemm_ye      <<<(NEV + 31)/32, 256, 0, stream>>>(ws);
  gemm_pq      <<<(NV + 63)/64, 256, 0, stream>>>(X, X0, Wb, ws, out);
  vertex_fused <<<NV/4, 256, 0, stream>>>(Ye, offV, PV, out);
}